// Round 1
// baseline (2807.727 us; speedup 1.0000x reference)
//
#include <hip/hip_runtime.h>
#include <hip/hip_bf16.h>

// Problem constants (fixed by the reference file)
#define BS   2
#define T    3
#define CCH  256
#define HH   48
#define WW   48
#define NH   8
#define NP   4
#define NL   3
#define DH   32          // CCH/NH
#define HWP  (HH*WW)     // 2304
#define LQ   (T*HWP)     // 6912
#define NIMG (BS*T)      // 6

// ---------------------------------------------------------------------------
// Flow kernel: builds add[n][t][pix][l][2]
// ---------------------------------------------------------------------------
__global__ __launch_bounds__(256) void flow_kernel(
    const float* __restrict__ ff,   // (BS,2,2,48,48)
    const float* __restrict__ fb,   // (BS,2,2,48,48)
    float* __restrict__ addb)       // (BS,3,2304,3,2)
{
    int idx = blockIdx.x * 256 + threadIdx.x;   // n*2304 + pix
    if (idx >= BS * HWP) return;
    int n = idx / HWP, pix = idx % HWP;
    int y = pix / WW, x = pix % WW;

    auto F = [&](const float* base, int i, int c, int p) {
        return base[n * (2*2*HWP) + i * (2*HWP) + c * HWP + p];
    };

    float f01x = F(ff,0,0,pix), f01y = F(ff,0,1,pix);
    float f12x = F(ff,1,0,pix), f12y = F(ff,1,1,pix);
    float b10x = F(fb,0,0,pix), b10y = F(fb,0,1,pix);
    float b21x = F(fb,1,0,pix), b21y = F(fb,1,1,pix);

    // warp(img=base[i], flow at this pixel) with align_corners=True + border pad.
    // Mirror the reference's normalize/unnormalize roundtrip in fp32.
    auto bil = [&](const float* base, int i, float fx, float fy, float* ox, float* oy) {
        float vx = (float)x + fx;
        float vy = (float)y + fy;
        float gx = 2.0f * vx / (float)(WW - 1) - 1.0f;
        float gy = 2.0f * vy / (float)(HH - 1) - 1.0f;
        float px = (gx + 1.0f) * 0.5f * (float)(WW - 1);
        float py = (gy + 1.0f) * 0.5f * (float)(HH - 1);
        px = fminf(fmaxf(px, 0.0f), (float)(WW - 1));
        py = fminf(fmaxf(py, 0.0f), (float)(HH - 1));
        float x0f = floorf(px), y0f = floorf(py);
        float wx1 = px - x0f, wx0 = 1.0f - wx1;
        float wy1 = py - y0f, wy0 = 1.0f - wy1;
        int xi0 = (int)x0f, yi0 = (int)y0f;
        int xc0 = min(max(xi0, 0), WW-1), xc1 = min(max(xi0+1, 0), WW-1);
        int yc0 = min(max(yi0, 0), HH-1), yc1 = min(max(yi0+1, 0), HH-1);
        float r[2];
        #pragma unroll
        for (int c = 0; c < 2; ++c) {
            float v00 = F(base, i, c, yc0*WW + xc0);
            float v10 = F(base, i, c, yc0*WW + xc1);
            float v01 = F(base, i, c, yc1*WW + xc0);
            float v11 = F(base, i, c, yc1*WW + xc1);
            r[c] = v00*(wx0*wy0) + v10*(wx1*wy0) + v01*(wx0*wy1) + v11*(wx1*wy1);
        }
        *ox = r[0]; *oy = r[1];
    };

    float wfx, wfy; bil(ff, 1, f01x, f01y, &wfx, &wfy);   // warp(f12, f01)
    float f02x = f01x + wfx, f02y = f01y + wfy;
    float wbx, wby; bil(fb, 0, b21x, b21y, &wbx, &wby);   // warp(b10, b21)
    float b20x = b21x + wbx, b20y = b21y + wby;

    float* A = addb + n * (3*HWP*6) + pix * 6;
    const int TS = HWP * 6;
    // t=0: [0, f01, f02]
    A[0] = 0.f;   A[1] = 0.f;   A[2] = f01x; A[3] = f01y; A[4] = f02x; A[5] = f02y;
    // t=1: [b10, 0, f12]
    A[TS+0] = b10x; A[TS+1] = b10y; A[TS+2] = 0.f; A[TS+3] = 0.f; A[TS+4] = f12x; A[TS+5] = f12y;
    // t=2: [b20, b21, 0]
    A[2*TS+0] = b20x; A[2*TS+1] = b20y; A[2*TS+2] = b21x; A[2*TS+3] = b21y; A[2*TS+4] = 0.f; A[2*TS+5] = 0.f;
}

// ---------------------------------------------------------------------------
// Direct 3x3 SAME conv, fp32, LDS-staged.
// Block: OCB output channels x 2 rows x 48 px (256 threads).
// MODE 0: value conv  -> V[(t*BS+n)*NH+head][y][x][d]   (channel-last, +mask)
// MODE 1: offset conv -> offb[n][q][192]
// MODE 2: attn conv   -> attnb[n][q][96]
// MODE 3: out conv    -> NCHW d_out
// ---------------------------------------------------------------------------
template<int OCB, int MODE>
__global__ __launch_bounds__(256) void conv3x3(
    const float* __restrict__ in,    // (NIMG,256,48,48)
    const float* __restrict__ wgt,   // (Cout,256,3,3)
    const float* __restrict__ bias,  // (Cout)
    float* __restrict__ out,
    const unsigned char* __restrict__ mask)  // MODE 0 only
{
    constexpr int RB   = 2;
    constexpr int NSUB = 256 / OCB;
    constexpr int XCH  = NSUB / RB;      // x-chunks per row
    constexpr int PPT  = WW / XCH;       // pixels per thread
    constexpr int ICB  = 8;
    constexpr int WSTR = ICB*9 + 1;      // 73: bank-conflict-free weight stride

    __shared__ float in_s[ICB][RB+2][WW+2];
    __shared__ float w_s[OCB][WSTR];

    const int ocb = blockIdx.x, ytile = blockIdx.y, img = blockIdx.z;
    const int y0  = ytile * RB;
    const int oc0 = ocb * OCB;
    const int tid = threadIdx.x;
    const int ocl = tid % OCB;
    const int sub = tid / OCB;
    const int r   = sub / XCH;
    const int xh  = sub % XCH;
    const int x0  = xh * PPT;

    const float* inI = in + (size_t)img * CCH * HWP;

    float acc[PPT];
    #pragma unroll
    for (int j = 0; j < PPT; ++j) acc[j] = 0.f;

    for (int ic0 = 0; ic0 < CCH; ic0 += ICB) {
        __syncthreads();
        // stage input rows y0-1 .. y0+RB, zero-padded, (WW+2) wide
        for (int idx = tid; idx < ICB*(RB+2)*(WW+2); idx += 256) {
            int ic  = idx / ((RB+2)*(WW+2));
            int rem = idx % ((RB+2)*(WW+2));
            int rr  = rem / (WW+2);
            int cc  = rem % (WW+2);
            int gy  = y0 - 1 + rr;
            int gx  = cc - 1;
            float v = 0.f;
            if (gy >= 0 && gy < HH && gx >= 0 && gx < WW)
                v = inI[(ic0+ic)*HWP + gy*WW + gx];
            in_s[ic][rr][cc] = v;
        }
        // stage weights
        for (int idx = tid; idx < OCB*ICB*9; idx += 256) {
            int o = idx / (ICB*9);
            int k = idx % (ICB*9);
            w_s[o][k] = wgt[(size_t)(oc0+o)*CCH*9 + ic0*9 + k];
        }
        __syncthreads();

        #pragma unroll
        for (int ic = 0; ic < ICB; ++ic) {
            #pragma unroll
            for (int ky = 0; ky < 3; ++ky) {
                float w0 = w_s[ocl][ic*9 + ky*3 + 0];
                float w1 = w_s[ocl][ic*9 + ky*3 + 1];
                float w2 = w_s[ocl][ic*9 + ky*3 + 2];
                const float* row = &in_s[ic][r+ky][x0];
                float rv[PPT+2];
                #pragma unroll
                for (int j = 0; j < PPT+2; ++j) rv[j] = row[j];
                #pragma unroll
                for (int j = 0; j < PPT; ++j)
                    acc[j] += w0*rv[j] + w1*rv[j+1] + w2*rv[j+2];
            }
        }
    }

    const int n = img / T, t = img % T;
    const int oc = oc0 + ocl;
    const float bv = bias[oc];
    #pragma unroll
    for (int j = 0; j < PPT; ++j) {
        int x = x0 + j, y = y0 + r;
        float v = acc[j] + bv;
        if (MODE == 0) {
            int q = t*HWP + y*WW + x;
            if (mask[n*LQ + q]) v = 0.f;
            int head = oc >> 5, d = oc & 31;
            int vimg = (t*BS + n)*NH + head;
            out[((size_t)(vimg*HWP) + y*WW + x)*DH + d] = v;
        } else if (MODE == 1) {
            int q = t*HWP + y*WW + x;
            out[((size_t)n*LQ + q)*192 + oc] = v;
        } else if (MODE == 2) {
            int q = t*HWP + y*WW + x;
            out[((size_t)n*LQ + q)*96 + oc] = v;
        } else {
            out[((size_t)img*CCH + oc)*HWP + y*WW + x] = v;
        }
    }
}

// ---------------------------------------------------------------------------
// Deformable sampling + softmax + weighted sum.
// One block per (n,q); threads = head(8) x d(32).
// Writes mid in NCHW seq layout: mid[(n*T+t)*256 + head*32+d][pix]
// ---------------------------------------------------------------------------
__global__ __launch_bounds__(256) void sample_kernel(
    const float* __restrict__ V,      // (48 imgs, 48,48, 32) channel-last
    const float* __restrict__ offb,   // (BS, LQ, 192)
    const float* __restrict__ attnb,  // (BS, LQ, 96)
    const float* __restrict__ addb,   // (BS, 3, 2304, 3, 2)
    const float* __restrict__ refp,   // (BS, LQ, 3, 2)
    float* __restrict__ mid)          // (6, 256, 2304)
{
    int blk = blockIdx.x;             // n*LQ + q
    int n = blk / LQ, q = blk % LQ;
    int t = q / HWP, pix = q % HWP;
    int tid = threadIdx.x;
    int head = tid >> 5, d = tid & 31;

    // softmax over the 12 logits of this head
    const float* al = attnb + ((size_t)n*LQ + q)*96 + head*12;
    float lg[12];
    float m = -1e30f;
    #pragma unroll
    for (int j = 0; j < 12; ++j) { lg[j] = al[j]; m = fmaxf(m, lg[j]); }
    float s = 0.f;
    #pragma unroll
    for (int j = 0; j < 12; ++j) { lg[j] = expf(lg[j] - m); s += lg[j]; }
    float inv = 1.0f / s;

    const float* ofl = offb + ((size_t)n*LQ + q)*192 + head*24;
    const float* ad  = addb + ((size_t)n*3*HWP + t*HWP + pix) * 6;
    const float* rp  = refp + ((size_t)n*LQ + q)*6;

    float acc = 0.f;
    #pragma unroll
    for (int l = 0; l < NL; ++l) {
        float refx = rp[l*2+0], refy = rp[l*2+1];
        float addx = ad[l*2+0], addy = ad[l*2+1];
        const float* Vi = V + (size_t)((l*BS + n)*NH + head) * HWP * DH;
        #pragma unroll
        for (int p = 0; p < NP; ++p) {
            float ox = ofl[(l*4+p)*2+0] + addx;
            float oy = ofl[(l*4+p)*2+1] + addy;
            // mirror the reference arithmetic exactly
            float locx = refx + ox * (1.0f/48.0f);
            float locy = refy + oy * (1.0f/48.0f);
            float gx = 2.0f*locx - 1.0f;
            float gy = 2.0f*locy - 1.0f;
            float px = ((gx + 1.0f) * 48.0f - 1.0f) * 0.5f;
            float py = ((gy + 1.0f) * 48.0f - 1.0f) * 0.5f;
            float x0f = floorf(px), y0f = floorf(py);
            float wx1 = px - x0f, wx0 = 1.0f - wx1;
            float wy1 = py - y0f, wy0 = 1.0f - wy1;
            int xi0 = (int)x0f, yi0 = (int)y0f;
            bool vx0 = (x0f >= 0.0f)      && (x0f <= 47.0f);
            bool vx1 = (x0f+1.f >= 0.0f)  && (x0f+1.f <= 47.0f);
            bool vy0 = (y0f >= 0.0f)      && (y0f <= 47.0f);
            bool vy1 = (y0f+1.f >= 0.0f)  && (y0f+1.f <= 47.0f);
            int xc0 = min(max(xi0, 0), 47),   xc1 = min(max(xi0+1, 0), 47);
            int yc0 = min(max(yi0, 0), 47),   yc1 = min(max(yi0+1, 0), 47);
            float v00 = (vx0 && vy0) ? Vi[(yc0*WW + xc0)*DH + d] : 0.f;
            float v10 = (vx1 && vy0) ? Vi[(yc0*WW + xc1)*DH + d] : 0.f;
            float v01 = (vx0 && vy1) ? Vi[(yc1*WW + xc0)*DH + d] : 0.f;
            float v11 = (vx1 && vy1) ? Vi[(yc1*WW + xc1)*DH + d] : 0.f;
            float sampled = v00*(wx0*wy0) + v10*(wx1*wy0) + v01*(wx0*wy1) + v11*(wx1*wy1);
            acc += (lg[l*4+p] * inv) * sampled;
        }
    }
    mid[((size_t)(n*T + t)*CCH + (head*DH + d))*HWP + pix] = acc;
}

// ---------------------------------------------------------------------------
extern "C" void kernel_launch(void* const* d_in, const int* in_sizes, int n_in,
                              void* d_out, int out_size, void* d_ws, size_t ws_size,
                              hipStream_t stream) {
    const float* query  = (const float*)d_in[0];
    const float* refp   = (const float*)d_in[1];
    const float* inputf = (const float*)d_in[2];
    // d_in[3] spatial shapes, d_in[4] level start idx: compile-time constants here
    const unsigned char* mask = (const unsigned char*)d_in[5];
    const float* ff     = (const float*)d_in[6];
    const float* fb     = (const float*)d_in[7];
    const float* w_off  = (const float*)d_in[8];
    const float* b_off  = (const float*)d_in[9];
    const float* w_attn = (const float*)d_in[10];
    const float* b_attn = (const float*)d_in[11];
    const float* w_val  = (const float*)d_in[12];
    const float* b_val  = (const float*)d_in[13];
    const float* w_out  = (const float*)d_in[14];
    const float* b_out  = (const float*)d_in[15];

    float* ws    = (float*)d_ws;
    float* V     = ws;                       // 48*2304*32      = 3,538,944
    float* offb  = V     + 3538944;          // 2*6912*192      = 2,654,208
    float* attnb = offb  + 2654208;          // 2*6912*96       = 1,327,104
    float* addb  = attnb + 1327104;          // 2*3*2304*3*2    =    82,944
    float* mid   = addb  + 82944;            // 6*256*2304      = 3,538,944
    float* outp  = (float*)d_out;

    flow_kernel<<<(BS*HWP + 255)/256, 256, 0, stream>>>(ff, fb, addb);
    conv3x3<64,0><<<dim3(CCH/64, HH/2, NIMG), 256, 0, stream>>>(inputf, w_val, b_val, V, mask);
    conv3x3<64,1><<<dim3(192/64, HH/2, NIMG), 256, 0, stream>>>(query, w_off, b_off, offb, nullptr);
    conv3x3<32,2><<<dim3(96/32,  HH/2, NIMG), 256, 0, stream>>>(query, w_attn, b_attn, attnb, nullptr);
    sample_kernel<<<BS*LQ, 256, 0, stream>>>(V, offb, attnb, addb, refp, mid);
    conv3x3<64,3><<<dim3(CCH/64, HH/2, NIMG), 256, 0, stream>>>(mid, w_out, b_out, outp, nullptr);
}

// Round 2
// 616.471 us; speedup vs baseline: 4.5545x; 4.5545x over previous
//
#include <hip/hip_runtime.h>
#include <hip/hip_bf16.h>

#define BS   2
#define T    3
#define CCH  256
#define HH   48
#define WW   48
#define NH   8
#define NP   4
#define NL   3
#define DH   32
#define HWP  (HH*WW)     // 2304
#define LQ   (T*HWP)     // 6912
#define NIMG (BS*T)      // 6

typedef short v8s __attribute__((ext_vector_type(8)));
typedef float v4f __attribute__((ext_vector_type(4)));

__device__ __forceinline__ unsigned short f2b(float f) {
    unsigned u = __float_as_uint(f);
    return (unsigned short)((u + 0x7FFFu + ((u >> 16) & 1u)) >> 16);
}
__device__ __forceinline__ float b2f(unsigned short b) {
    return __uint_as_float((unsigned)b << 16);
}

// ---------------------------------------------------------------------------
// Flow kernel: builds add[n][t][pix][l][2]  (fp32, tiny)
// ---------------------------------------------------------------------------
__global__ __launch_bounds__(256) void flow_kernel(
    const float* __restrict__ ff, const float* __restrict__ fb,
    float* __restrict__ addb)
{
    int idx = blockIdx.x * 256 + threadIdx.x;
    if (idx >= BS * HWP) return;
    int n = idx / HWP, pix = idx % HWP;
    int y = pix / WW, x = pix % WW;

    auto F = [&](const float* base, int i, int c, int p) {
        return base[n * (2*2*HWP) + i * (2*HWP) + c * HWP + p];
    };

    float f01x = F(ff,0,0,pix), f01y = F(ff,0,1,pix);
    float f12x = F(ff,1,0,pix), f12y = F(ff,1,1,pix);
    float b10x = F(fb,0,0,pix), b10y = F(fb,0,1,pix);
    float b21x = F(fb,1,0,pix), b21y = F(fb,1,1,pix);

    auto bil = [&](const float* base, int i, float fx, float fy, float* ox, float* oy) {
        float vx = (float)x + fx;
        float vy = (float)y + fy;
        float gx = 2.0f * vx / (float)(WW - 1) - 1.0f;
        float gy = 2.0f * vy / (float)(HH - 1) - 1.0f;
        float px = (gx + 1.0f) * 0.5f * (float)(WW - 1);
        float py = (gy + 1.0f) * 0.5f * (float)(HH - 1);
        px = fminf(fmaxf(px, 0.0f), (float)(WW - 1));
        py = fminf(fmaxf(py, 0.0f), (float)(HH - 1));
        float x0f = floorf(px), y0f = floorf(py);
        float wx1 = px - x0f, wx0 = 1.0f - wx1;
        float wy1 = py - y0f, wy0 = 1.0f - wy1;
        int xi0 = (int)x0f, yi0 = (int)y0f;
        int xc0 = min(max(xi0, 0), WW-1), xc1 = min(max(xi0+1, 0), WW-1);
        int yc0 = min(max(yi0, 0), HH-1), yc1 = min(max(yi0+1, 0), HH-1);
        float r[2];
        #pragma unroll
        for (int c = 0; c < 2; ++c) {
            float v00 = F(base, i, c, yc0*WW + xc0);
            float v10 = F(base, i, c, yc0*WW + xc1);
            float v01 = F(base, i, c, yc1*WW + xc0);
            float v11 = F(base, i, c, yc1*WW + xc1);
            r[c] = v00*(wx0*wy0) + v10*(wx1*wy0) + v01*(wx0*wy1) + v11*(wx1*wy1);
        }
        *ox = r[0]; *oy = r[1];
    };

    float wfx, wfy; bil(ff, 1, f01x, f01y, &wfx, &wfy);
    float f02x = f01x + wfx, f02y = f01y + wfy;
    float wbx, wby; bil(fb, 0, b21x, b21y, &wbx, &wby);
    float b20x = b21x + wbx, b20y = b21y + wby;

    float* A = addb + n * (3*HWP*6) + pix * 6;
    const int TS = HWP * 6;
    A[0] = 0.f;   A[1] = 0.f;   A[2] = f01x; A[3] = f01y; A[4] = f02x; A[5] = f02y;
    A[TS+0] = b10x; A[TS+1] = b10y; A[TS+2] = 0.f; A[TS+3] = 0.f; A[TS+4] = f12x; A[TS+5] = f12y;
    A[2*TS+0] = b20x; A[2*TS+1] = b20y; A[2*TS+2] = b21x; A[2*TS+3] = b21y; A[2*TS+4] = 0.f; A[2*TS+5] = 0.f;
}

// ---------------------------------------------------------------------------
// Weight transform: w[oc][ic][3][3] fp32 -> Wb[k][oc][ic] bf16
// ---------------------------------------------------------------------------
__global__ __launch_bounds__(256) void wcvt_kernel(
    const float* __restrict__ src, unsigned short* __restrict__ dst, int M)
{
    int idx = blockIdx.x * 256 + threadIdx.x;
    if (idx >= 9 * M * 256) return;
    int k  = idx / (M * 256);
    int oc = (idx / 256) % M;
    int ic = idx % 256;
    dst[idx] = f2b(src[(oc * 256 + ic) * 9 + k]);
}

// ---------------------------------------------------------------------------
// Input transform: in[img][ic][px] fp32 -> out[img][px][ic] bf16 (channel-last)
// ---------------------------------------------------------------------------
__global__ __launch_bounds__(256) void tcvt_kernel(
    const float* __restrict__ src, unsigned short* __restrict__ dst)
{
    __shared__ float lds[32][33];
    int px0 = blockIdx.x * 32, ic0 = blockIdx.y * 32, img = blockIdx.z;
    int t = threadIdx.x;
    #pragma unroll
    for (int s = 0; s < 4; ++s) {
        int icl = (t >> 5) + s * 8, pxl = t & 31;
        lds[icl][pxl] = src[((size_t)img * 256 + ic0 + icl) * HWP + px0 + pxl];
    }
    __syncthreads();
    #pragma unroll
    for (int s = 0; s < 4; ++s) {
        int pxl = (t >> 5) + s * 8, icl = t & 31;
        dst[((size_t)img * HWP + px0 + pxl) * 256 + ic0 + icl] = f2b(lds[icl][pxl]);
    }
}

// ---------------------------------------------------------------------------
// Implicit-GEMM 3x3 SAME conv via MFMA 16x16x32 bf16.
// Block: 4 waves; wave tile = 64 oc x 32 px; block tile = 64 oc x 128 px.
// A = Wb[k][oc][ic] (K=ic contiguous). B = inb[img][px'][ic] with px' the
// shifted source pixel for tap k, zeroed at borders.
// MODE 0: V bf16 [48][2304][32] (+mask)   MODE 1: offb f32 [n][q][192]
// MODE 2: attnb f32 [n][q][96]            MODE 3: d_out f32 NCHW
// ---------------------------------------------------------------------------
template<int M, int MODE>
__global__ __launch_bounds__(256) void convmfma(
    const unsigned short* __restrict__ inb,
    const unsigned short* __restrict__ Wb,
    const float* __restrict__ bias,
    void* __restrict__ outp,
    const unsigned char* __restrict__ mask)
{
    const int tid  = threadIdx.x;
    const int lane = tid & 63;
    const int wv   = tid >> 6;
    const int img  = blockIdx.z;
    const int oc0  = blockIdx.x * 64;
    const int pxb  = blockIdx.y * 128 + wv * 32;
    const int row  = lane & 15;
    const int g    = lane >> 4;

    const unsigned short* inI = inb + (size_t)img * HWP * 256;

    v4f acc[4][2];
    #pragma unroll
    for (int m = 0; m < 4; ++m)
        #pragma unroll
        for (int p = 0; p < 2; ++p)
            #pragma unroll
            for (int e = 0; e < 4; ++e) acc[m][p][e] = 0.f;

    int px[2], py_[2], pxx[2];
    #pragma unroll
    for (int p = 0; p < 2; ++p) {
        px[p]  = pxb + p * 16 + row;
        py_[p] = px[p] / 48;
        pxx[p] = px[p] % 48;
    }
    int ocl[4];
    #pragma unroll
    for (int m = 0; m < 4; ++m) {
        int oc = oc0 + m * 16 + row;
        ocl[m] = (oc < M) ? oc : (M - 1);
    }

    v8s bz;
    #pragma unroll
    for (int j = 0; j < 8; ++j) bz[j] = 0;

    for (int k = 0; k < 9; ++k) {
        int dy = k / 3 - 1, dx = k % 3 - 1;
        const unsigned short* wk = Wb + (size_t)k * M * 256;
        int sp[2]; bool val[2];
        #pragma unroll
        for (int p = 0; p < 2; ++p) {
            int xx = pxx[p] + dx, yy = py_[p] + dy;
            val[p] = ((unsigned)xx < 48u) && ((unsigned)yy < 48u);
            sp[p]  = val[p] ? (yy * 48 + xx) : 0;
        }
        #pragma unroll
        for (int icb = 0; icb < 8; ++icb) {
            int ic = icb * 32 + g * 8;
            v8s a[4], b[2];
            #pragma unroll
            for (int m = 0; m < 4; ++m)
                a[m] = *(const v8s*)(wk + ocl[m] * 256 + ic);
            #pragma unroll
            for (int p = 0; p < 2; ++p) {
                v8s tb = *(const v8s*)(inI + sp[p] * 256 + ic);
                b[p] = val[p] ? tb : bz;
            }
            #pragma unroll
            for (int m = 0; m < 4; ++m)
                #pragma unroll
                for (int p = 0; p < 2; ++p)
                    acc[m][p] = __builtin_amdgcn_mfma_f32_16x16x32_bf16(a[m], b[p], acc[m][p], 0, 0, 0);
        }
    }

    const int n = img / T, t = img % T;
    #pragma unroll
    for (int m = 0; m < 4; ++m) {
        #pragma unroll
        for (int p = 0; p < 2; ++p) {
            int q = t * HWP + px[p];
            #pragma unroll
            for (int r = 0; r < 4; ++r) {
                int occ = oc0 + m * 16 + g * 4 + r;
                if (occ >= M) continue;
                float v = acc[m][p][r] + bias[occ];
                if (MODE == 0) {
                    if (mask[n * LQ + q]) v = 0.f;
                    int head = occ >> 5, d = occ & 31;
                    ((unsigned short*)outp)[(((size_t)(t * BS + n) * NH + head) * HWP + px[p]) * 32 + d] = f2b(v);
                } else if (MODE == 1) {
                    ((float*)outp)[((size_t)n * LQ + q) * 192 + occ] = v;
                } else if (MODE == 2) {
                    ((float*)outp)[((size_t)n * LQ + q) * 96 + occ] = v;
                } else {
                    ((float*)outp)[((size_t)img * CCH + occ) * HWP + px[p]] = v;
                }
            }
        }
    }
}

// ---------------------------------------------------------------------------
// Deformable sampling + softmax + weighted sum. Block per (n,q), thread (head,d).
// V bf16 channel-last; writes midb bf16 channel-last [img][pix][ch].
// ---------------------------------------------------------------------------
__global__ __launch_bounds__(256) void sample_kernel(
    const unsigned short* __restrict__ V,
    const float* __restrict__ offb,
    const float* __restrict__ attnb,
    const float* __restrict__ addb,
    const float* __restrict__ refp,
    unsigned short* __restrict__ midb)
{
    int blk = blockIdx.x;
    int n = blk / LQ, q = blk % LQ;
    int t = q / HWP, pix = q % HWP;
    int tid = threadIdx.x;
    int head = tid >> 5, d = tid & 31;

    const float* al = attnb + ((size_t)n * LQ + q) * 96 + head * 12;
    float lg[12];
    float m = -1e30f;
    #pragma unroll
    for (int j = 0; j < 12; ++j) { lg[j] = al[j]; m = fmaxf(m, lg[j]); }
    float s = 0.f;
    #pragma unroll
    for (int j = 0; j < 12; ++j) { lg[j] = expf(lg[j] - m); s += lg[j]; }
    float inv = 1.0f / s;

    const float* ofl = offb + ((size_t)n * LQ + q) * 192 + head * 24;
    const float* ad  = addb + ((size_t)n * 3 * HWP + t * HWP + pix) * 6;
    const float* rp  = refp + ((size_t)n * LQ + q) * 6;

    float acc = 0.f;
    #pragma unroll
    for (int l = 0; l < NL; ++l) {
        float refx = rp[l*2+0], refy = rp[l*2+1];
        float addx = ad[l*2+0], addy = ad[l*2+1];
        const unsigned short* Vi = V + (size_t)((l * BS + n) * NH + head) * HWP * DH;
        #pragma unroll
        for (int p = 0; p < NP; ++p) {
            float ox = ofl[(l*4+p)*2+0] + addx;
            float oy = ofl[(l*4+p)*2+1] + addy;
            float locx = refx + ox * (1.0f/48.0f);
            float locy = refy + oy * (1.0f/48.0f);
            float gx = 2.0f*locx - 1.0f;
            float gy = 2.0f*locy - 1.0f;
            float pxf = ((gx + 1.0f) * 48.0f - 1.0f) * 0.5f;
            float pyf = ((gy + 1.0f) * 48.0f - 1.0f) * 0.5f;
            float x0f = floorf(pxf), y0f = floorf(pyf);
            float wx1 = pxf - x0f, wx0 = 1.0f - wx1;
            float wy1 = pyf - y0f, wy0 = 1.0f - wy1;
            int xi0 = (int)x0f, yi0 = (int)y0f;
            bool vx0 = (x0f >= 0.0f)     && (x0f <= 47.0f);
            bool vx1 = (x0f+1.f >= 0.0f) && (x0f+1.f <= 47.0f);
            bool vy0 = (y0f >= 0.0f)     && (y0f <= 47.0f);
            bool vy1 = (y0f+1.f >= 0.0f) && (y0f+1.f <= 47.0f);
            int xc0 = min(max(xi0, 0), 47),   xc1 = min(max(xi0+1, 0), 47);
            int yc0 = min(max(yi0, 0), 47),   yc1 = min(max(yi0+1, 0), 47);
            float v00 = (vx0 && vy0) ? b2f(Vi[(yc0*WW + xc0)*DH + d]) : 0.f;
            float v10 = (vx1 && vy0) ? b2f(Vi[(yc0*WW + xc1)*DH + d]) : 0.f;
            float v01 = (vx0 && vy1) ? b2f(Vi[(yc1*WW + xc0)*DH + d]) : 0.f;
            float v11 = (vx1 && vy1) ? b2f(Vi[(yc1*WW + xc1)*DH + d]) : 0.f;
            float sampled = v00*(wx0*wy0) + v10*(wx1*wy0) + v01*(wx0*wy1) + v11*(wx1*wy1);
            acc += (lg[l*4+p] * inv) * sampled;
        }
    }
    midb[((size_t)(n * T + t) * HWP + pix) * 256 + head * DH + d] = f2b(acc);
}

// ---------------------------------------------------------------------------
extern "C" void kernel_launch(void* const* d_in, const int* in_sizes, int n_in,
                              void* d_out, int out_size, void* d_ws, size_t ws_size,
                              hipStream_t stream) {
    const float* query  = (const float*)d_in[0];
    const float* refp   = (const float*)d_in[1];
    const float* inputf = (const float*)d_in[2];
    const unsigned char* mask = (const unsigned char*)d_in[5];
    const float* ff     = (const float*)d_in[6];
    const float* fb     = (const float*)d_in[7];
    const float* w_off  = (const float*)d_in[8];
    const float* b_off  = (const float*)d_in[9];
    const float* w_attn = (const float*)d_in[10];
    const float* b_attn = (const float*)d_in[11];
    const float* w_val  = (const float*)d_in[12];
    const float* b_val  = (const float*)d_in[13];
    const float* w_out  = (const float*)d_in[14];
    const float* b_out  = (const float*)d_in[15];

    char* w = (char*)d_ws;
    float* offb  = (float*)w;           w += (size_t)BS*LQ*192*4;      // 10,616,832
    float* attnb = (float*)w;           w += (size_t)BS*LQ*96*4;       //  5,308,416
    float* addb  = (float*)w;           w += (size_t)BS*3*HWP*6*4;     //    331,776
    unsigned short* V      = (unsigned short*)w; w += (size_t)48*HWP*DH*2;   // 7,077,888
    unsigned short* inb_q  = (unsigned short*)w; w += (size_t)NIMG*HWP*256*2;// 7,077,888
    unsigned short* inb_v  = (unsigned short*)w; w += (size_t)NIMG*HWP*256*2;// 7,077,888 (midb aliases)
    unsigned short* midb   = inb_v;  // alias: value conv finishes reading before sampler writes
    unsigned short* Wb_val = (unsigned short*)w; w += (size_t)9*256*256*2;   // 1,179,648
    unsigned short* Wb_off = (unsigned short*)w; w += (size_t)9*192*256*2;   //   884,736
    unsigned short* Wb_att = (unsigned short*)w; w += (size_t)9*96*256*2;    //   442,368
    unsigned short* Wb_out = (unsigned short*)w; w += (size_t)9*256*256*2;   // 1,179,648
    float* outp = (float*)d_out;

    flow_kernel<<<(BS*HWP + 255)/256, 256, 0, stream>>>(ff, fb, addb);
    wcvt_kernel<<<9*256, 256, 0, stream>>>(w_val, Wb_val, 256);
    wcvt_kernel<<<9*192, 256, 0, stream>>>(w_off, Wb_off, 192);
    wcvt_kernel<<<9*96,  256, 0, stream>>>(w_attn, Wb_att, 96);
    wcvt_kernel<<<9*256, 256, 0, stream>>>(w_out, Wb_out, 256);
    tcvt_kernel<<<dim3(HWP/32, 8, NIMG), 256, 0, stream>>>(inputf, inb_v);
    tcvt_kernel<<<dim3(HWP/32, 8, NIMG), 256, 0, stream>>>(query,  inb_q);

    convmfma<256,0><<<dim3(4, 18, NIMG), 256, 0, stream>>>(inb_v, Wb_val, b_val, (void*)V, mask);
    convmfma<192,1><<<dim3(3, 18, NIMG), 256, 0, stream>>>(inb_q, Wb_off, b_off, (void*)offb, nullptr);
    convmfma<96, 2><<<dim3(2, 18, NIMG), 256, 0, stream>>>(inb_q, Wb_att, b_attn, (void*)attnb, nullptr);

    sample_kernel<<<BS*LQ, 256, 0, stream>>>(V, offb, attnb, addb, refp, midb);

    convmfma<256,3><<<dim3(4, 18, NIMG), 256, 0, stream>>>(midb, Wb_out, b_out, (void*)outp, nullptr);
}

// Round 3
// 441.848 us; speedup vs baseline: 6.3545x; 1.3952x over previous
//
#include <hip/hip_runtime.h>
#include <hip/hip_bf16.h>

#define BS   2
#define T    3
#define CCH  256
#define HH   48
#define WW   48
#define NH   8
#define NP   4
#define NL   3
#define DH   32
#define HWP  (HH*WW)     // 2304
#define LQ   (T*HWP)     // 6912
#define NIMG (BS*T)      // 6

typedef short v8s __attribute__((ext_vector_type(8)));
typedef float v4f __attribute__((ext_vector_type(4)));
typedef float v2f __attribute__((ext_vector_type(2)));
typedef unsigned int v2u __attribute__((ext_vector_type(2)));

__device__ __forceinline__ unsigned short f2b(float f) {
    unsigned u = __float_as_uint(f);
    return (unsigned short)((u + 0x7FFFu + ((u >> 16) & 1u)) >> 16);
}

// ---------------------------------------------------------------------------
// Flow kernel: builds add[n][t][pix][l][2]  (fp32, tiny)
// ---------------------------------------------------------------------------
__global__ __launch_bounds__(256) void flow_kernel(
    const float* __restrict__ ff, const float* __restrict__ fb,
    float* __restrict__ addb)
{
    int idx = blockIdx.x * 256 + threadIdx.x;
    if (idx >= BS * HWP) return;
    int n = idx / HWP, pix = idx % HWP;
    int y = pix / WW, x = pix % WW;

    auto F = [&](const float* base, int i, int c, int p) {
        return base[n * (2*2*HWP) + i * (2*HWP) + c * HWP + p];
    };

    float f01x = F(ff,0,0,pix), f01y = F(ff,0,1,pix);
    float f12x = F(ff,1,0,pix), f12y = F(ff,1,1,pix);
    float b10x = F(fb,0,0,pix), b10y = F(fb,0,1,pix);
    float b21x = F(fb,1,0,pix), b21y = F(fb,1,1,pix);

    auto bil = [&](const float* base, int i, float fx, float fy, float* ox, float* oy) {
        float vx = (float)x + fx;
        float vy = (float)y + fy;
        float gx = 2.0f * vx / (float)(WW - 1) - 1.0f;
        float gy = 2.0f * vy / (float)(HH - 1) - 1.0f;
        float px = (gx + 1.0f) * 0.5f * (float)(WW - 1);
        float py = (gy + 1.0f) * 0.5f * (float)(HH - 1);
        px = fminf(fmaxf(px, 0.0f), (float)(WW - 1));
        py = fminf(fmaxf(py, 0.0f), (float)(HH - 1));
        float x0f = floorf(px), y0f = floorf(py);
        float wx1 = px - x0f, wx0 = 1.0f - wx1;
        float wy1 = py - y0f, wy0 = 1.0f - wy1;
        int xi0 = (int)x0f, yi0 = (int)y0f;
        int xc0 = min(max(xi0, 0), WW-1), xc1 = min(max(xi0+1, 0), WW-1);
        int yc0 = min(max(yi0, 0), HH-1), yc1 = min(max(yi0+1, 0), HH-1);
        float r[2];
        #pragma unroll
        for (int c = 0; c < 2; ++c) {
            float v00 = F(base, i, c, yc0*WW + xc0);
            float v10 = F(base, i, c, yc0*WW + xc1);
            float v01 = F(base, i, c, yc1*WW + xc0);
            float v11 = F(base, i, c, yc1*WW + xc1);
            r[c] = v00*(wx0*wy0) + v10*(wx1*wy0) + v01*(wx0*wy1) + v11*(wx1*wy1);
        }
        *ox = r[0]; *oy = r[1];
    };

    float wfx, wfy; bil(ff, 1, f01x, f01y, &wfx, &wfy);
    float f02x = f01x + wfx, f02y = f01y + wfy;
    float wbx, wby; bil(fb, 0, b21x, b21y, &wbx, &wby);
    float b20x = b21x + wbx, b20y = b21y + wby;

    float* A = addb + n * (3*HWP*6) + pix * 6;
    const int TS = HWP * 6;
    A[0] = 0.f;   A[1] = 0.f;   A[2] = f01x; A[3] = f01y; A[4] = f02x; A[5] = f02y;
    A[TS+0] = b10x; A[TS+1] = b10y; A[TS+2] = 0.f; A[TS+3] = 0.f; A[TS+4] = f12x; A[TS+5] = f12y;
    A[2*TS+0] = b20x; A[2*TS+1] = b20y; A[2*TS+2] = b21x; A[2*TS+3] = b21y; A[2*TS+4] = 0.f; A[2*TS+5] = 0.f;
}

// ---------------------------------------------------------------------------
// Weight transform: oc<M0 from s0, else s1. dst[k][oc][ic] bf16.
// ---------------------------------------------------------------------------
__global__ __launch_bounds__(256) void wcvt2_kernel(
    const float* __restrict__ s0, const float* __restrict__ s1,
    unsigned short* __restrict__ dst, int M0, int M)
{
    int idx = blockIdx.x * 256 + threadIdx.x;
    if (idx >= 9 * M * 256) return;
    int k  = idx / (M * 256);
    int oc = (idx / 256) % M;
    int ic = idx % 256;
    float v = (oc < M0) ? s0[((size_t)oc * 256 + ic) * 9 + k]
                        : s1[((size_t)(oc - M0) * 256 + ic) * 9 + k];
    dst[idx] = f2b(v);
}

// ---------------------------------------------------------------------------
// Input transform: in[img][ic][px] fp32 -> out[img][px][ic] bf16
// ---------------------------------------------------------------------------
__global__ __launch_bounds__(256) void tcvt_kernel(
    const float* __restrict__ src, unsigned short* __restrict__ dst)
{
    __shared__ float lds[32][33];
    int px0 = blockIdx.x * 32, ic0 = blockIdx.y * 32, img = blockIdx.z;
    int t = threadIdx.x;
    #pragma unroll
    for (int s = 0; s < 4; ++s) {
        int icl = (t >> 5) + s * 8, pxl = t & 31;
        lds[icl][pxl] = src[((size_t)img * 256 + ic0 + icl) * HWP + px0 + pxl];
    }
    __syncthreads();
    #pragma unroll
    for (int s = 0; s < 4; ++s) {
        int pxl = (t >> 5) + s * 8, icl = t & 31;
        dst[((size_t)img * HWP + px0 + pxl) * 256 + ic0 + icl] = f2b(lds[icl][pxl]);
    }
}

// ---------------------------------------------------------------------------
// Implicit-GEMM 3x3 SAME conv via MFMA 16x16x32 bf16.
// Wave tile = 32 oc x 32 px; block = 4 waves side-by-side in px (32oc x 128px).
// MODE 0: V bf16 [48][2304][32] (+mask)
// MODE 1: fused offsets+attn (M=288): occ<192 -> offb f32, else attnb f32
// MODE 3: d_out f32 NCHW
// ---------------------------------------------------------------------------
template<int M, int MODE>
__global__ __launch_bounds__(256) void convmfma(
    const unsigned short* __restrict__ inb,
    const unsigned short* __restrict__ Wb,
    const float* __restrict__ bias,
    const float* __restrict__ bias2,
    void* __restrict__ outp,
    void* __restrict__ outp2,
    const unsigned char* __restrict__ mask)
{
    const int tid  = threadIdx.x;
    const int lane = tid & 63;
    const int wv   = tid >> 6;
    const int img  = blockIdx.z;
    const int oc0  = blockIdx.x * 32;
    const int pxb  = blockIdx.y * 128 + wv * 32;
    const int row  = lane & 15;
    const int g    = lane >> 4;

    const unsigned short* inI = inb + (size_t)img * HWP * 256;

    v4f acc[2][2];
    #pragma unroll
    for (int m = 0; m < 2; ++m)
        #pragma unroll
        for (int p = 0; p < 2; ++p)
            #pragma unroll
            for (int e = 0; e < 4; ++e) acc[m][p][e] = 0.f;

    int px[2], py_[2], pxx[2];
    #pragma unroll
    for (int p = 0; p < 2; ++p) {
        px[p]  = pxb + p * 16 + row;
        py_[p] = px[p] / 48;
        pxx[p] = px[p] % 48;
    }

    v8s bz;
    #pragma unroll
    for (int j = 0; j < 8; ++j) bz[j] = 0;

    for (int k = 0; k < 9; ++k) {
        int dy = k / 3 - 1, dx = k % 3 - 1;
        const unsigned short* wk = Wb + (size_t)k * M * 256;
        int sp[2]; bool val[2];
        #pragma unroll
        for (int p = 0; p < 2; ++p) {
            int xx = pxx[p] + dx, yy = py_[p] + dy;
            val[p] = ((unsigned)xx < 48u) && ((unsigned)yy < 48u);
            sp[p]  = val[p] ? (yy * 48 + xx) : 0;
        }
        #pragma unroll
        for (int icb = 0; icb < 8; ++icb) {
            int ic = icb * 32 + g * 8;
            v8s a[2], b[2];
            #pragma unroll
            for (int m = 0; m < 2; ++m)
                a[m] = *(const v8s*)(wk + (size_t)(oc0 + m * 16 + row) * 256 + ic);
            #pragma unroll
            for (int p = 0; p < 2; ++p) {
                v8s tb = *(const v8s*)(inI + (size_t)sp[p] * 256 + ic);
                b[p] = val[p] ? tb : bz;
            }
            #pragma unroll
            for (int m = 0; m < 2; ++m)
                #pragma unroll
                for (int p = 0; p < 2; ++p)
                    acc[m][p] = __builtin_amdgcn_mfma_f32_16x16x32_bf16(a[m], b[p], acc[m][p], 0, 0, 0);
        }
    }

    const int n = img / T, t = img % T;
    #pragma unroll
    for (int p = 0; p < 2; ++p) {
        int q = t * HWP + px[p];
        bool mk = (MODE == 0) ? (mask[n * LQ + q] != 0) : false;
        #pragma unroll
        for (int m = 0; m < 2; ++m) {
            int occ0 = oc0 + m * 16 + g * 4;
            if (MODE == 0) {
                unsigned short o[4];
                #pragma unroll
                for (int r = 0; r < 4; ++r) {
                    float v = acc[m][p][r] + bias[occ0 + r];
                    if (mk) v = 0.f;
                    o[r] = f2b(v);
                }
                int head = occ0 >> 5, d0 = occ0 & 31;
                v2u pk;
                pk[0] = (unsigned)o[0] | ((unsigned)o[1] << 16);
                pk[1] = (unsigned)o[2] | ((unsigned)o[3] << 16);
                *(v2u*)((unsigned short*)outp +
                        (((size_t)(t * BS + n) * NH + head) * HWP + px[p]) * 32 + d0) = pk;
            } else if (MODE == 1) {
                if (occ0 < 192) {
                    v4f v;
                    #pragma unroll
                    for (int r = 0; r < 4; ++r) v[r] = acc[m][p][r] + bias[occ0 + r];
                    *(v4f*)((float*)outp + ((size_t)n * LQ + q) * 192 + occ0) = v;
                } else {
                    v4f v;
                    #pragma unroll
                    for (int r = 0; r < 4; ++r) v[r] = acc[m][p][r] + bias2[occ0 - 192 + r];
                    *(v4f*)((float*)outp2 + ((size_t)n * LQ + q) * 96 + (occ0 - 192)) = v;
                }
            } else {
                #pragma unroll
                for (int r = 0; r < 4; ++r)
                    ((float*)outp)[((size_t)img * CCH + occ0 + r) * HWP + px[p]] =
                        acc[m][p][r] + bias[occ0 + r];
            }
        }
    }
}

// ---------------------------------------------------------------------------
// Deformable sampling. 8-lane group per (n,q,head); lane owns 4 d-channels.
// Block = 256 threads = 32 groups. Gathers are uint2 (8B) per corner.
// ---------------------------------------------------------------------------
__global__ __launch_bounds__(256) void sample_kernel(
    const unsigned short* __restrict__ V,
    const float* __restrict__ offb,
    const float* __restrict__ attnb,
    const float* __restrict__ addb,
    const float* __restrict__ refp,
    unsigned short* __restrict__ midb)
{
    const int tid = threadIdx.x;
    const int gid = tid >> 3, li = tid & 7;
    const int pair = blockIdx.x * 32 + gid;
    const int head = pair & 7;
    const int nq = pair >> 3;
    const int n = nq / LQ, q = nq % LQ;
    const int t = q / HWP, pix = q % HWP;

    // ---- params (vectorized) ----
    const float* al = attnb + ((size_t)n * LQ + q) * 96 + head * 12;
    float lg[12];
    {
        v4f t0 = *(const v4f*)al, t1 = *(const v4f*)(al + 4), t2 = *(const v4f*)(al + 8);
        #pragma unroll
        for (int j = 0; j < 4; ++j) { lg[j] = t0[j]; lg[4+j] = t1[j]; lg[8+j] = t2[j]; }
    }
    const float* ofp = offb + ((size_t)n * LQ + q) * 192 + head * 24;
    float of[24];
    #pragma unroll
    for (int j = 0; j < 6; ++j) {
        v4f v = *(const v4f*)(ofp + j * 4);
        #pragma unroll
        for (int e = 0; e < 4; ++e) of[j*4+e] = v[e];
    }
    const float* rpp = refp + ((size_t)n * LQ + q) * 6;
    const float* adp = addb + ((size_t)n * 3 * HWP + t * HWP + pix) * 6;
    float rp[6], ad[6];
    #pragma unroll
    for (int j = 0; j < 3; ++j) {
        v2f r = *(const v2f*)(rpp + j * 2);
        v2f a = *(const v2f*)(adp + j * 2);
        rp[j*2] = r[0]; rp[j*2+1] = r[1];
        ad[j*2] = a[0]; ad[j*2+1] = a[1];
    }

    // ---- softmax (normalization folded into lg) ----
    float m = lg[0];
    #pragma unroll
    for (int j = 1; j < 12; ++j) m = fmaxf(m, lg[j]);
    float s = 0.f;
    #pragma unroll
    for (int j = 0; j < 12; ++j) { lg[j] = expf(lg[j] - m); s += lg[j]; }
    float inv = 1.0f / s;
    #pragma unroll
    for (int j = 0; j < 12; ++j) lg[j] *= inv;

    float acc0 = 0.f, acc1 = 0.f, acc2 = 0.f, acc3 = 0.f;

    #pragma unroll
    for (int l = 0; l < 3; ++l) {
        float refx = rp[l*2+0], refy = rp[l*2+1];
        float addx = ad[l*2+0], addy = ad[l*2+1];
        const unsigned short* Vi =
            V + (size_t)((l * BS + n) * NH + head) * HWP * DH + li * 4;
        #pragma unroll
        for (int p = 0; p < 4; ++p) {
            float ox = of[(l*4+p)*2+0] + addx;
            float oy = of[(l*4+p)*2+1] + addy;
            float locx = refx + ox * (1.0f/48.0f);
            float locy = refy + oy * (1.0f/48.0f);
            float gx = 2.0f*locx - 1.0f;
            float gy = 2.0f*locy - 1.0f;
            float pxf = ((gx + 1.0f) * 48.0f - 1.0f) * 0.5f;
            float pyf = ((gy + 1.0f) * 48.0f - 1.0f) * 0.5f;
            float x0f = floorf(pxf), y0f = floorf(pyf);
            float wx1 = pxf - x0f, wx0 = 1.0f - wx1;
            float wy1 = pyf - y0f, wy0 = 1.0f - wy1;
            int xi0 = (int)x0f, yi0 = (int)y0f;
            bool vx0 = (x0f >= 0.0f)     && (x0f <= 47.0f);
            bool vx1 = (x0f+1.f >= 0.0f) && (x0f+1.f <= 47.0f);
            bool vy0 = (y0f >= 0.0f)     && (y0f <= 47.0f);
            bool vy1 = (y0f+1.f >= 0.0f) && (y0f+1.f <= 47.0f);
            int xc0 = min(max(xi0, 0), 47),   xc1 = min(max(xi0+1, 0), 47);
            int yc0 = min(max(yi0, 0), 47),   yc1 = min(max(yi0+1, 0), 47);
            float aw = lg[l*4+p];
            float w00 = (vx0 && vy0) ? wx0*wy0*aw : 0.f;
            float w10 = (vx1 && vy0) ? wx1*wy0*aw : 0.f;
            float w01 = (vx0 && vy1) ? wx0*wy1*aw : 0.f;
            float w11 = (vx1 && vy1) ? wx1*wy1*aw : 0.f;
            v2u u00 = *(const v2u*)(Vi + (yc0*WW + xc0)*DH);
            v2u u10 = *(const v2u*)(Vi + (yc0*WW + xc1)*DH);
            v2u u01 = *(const v2u*)(Vi + (yc1*WW + xc0)*DH);
            v2u u11 = *(const v2u*)(Vi + (yc1*WW + xc1)*DH);
            #pragma unroll
            for (int c = 0; c < 4; ++c) {
                v2u u = (c == 0) ? u00 : (c == 1) ? u10 : (c == 2) ? u01 : u11;
                float w = (c == 0) ? w00 : (c == 1) ? w10 : (c == 2) ? w01 : w11;
                float f0 = __uint_as_float(u[0] << 16);
                float f1 = __uint_as_float(u[0] & 0xFFFF0000u);
                float f2 = __uint_as_float(u[1] << 16);
                float f3 = __uint_as_float(u[1] & 0xFFFF0000u);
                acc0 += w * f0; acc1 += w * f1; acc2 += w * f2; acc3 += w * f3;
            }
        }
    }

    unsigned short o0 = f2b(acc0), o1 = f2b(acc1), o2 = f2b(acc2), o3 = f2b(acc3);
    v2u pk;
    pk[0] = (unsigned)o0 | ((unsigned)o1 << 16);
    pk[1] = (unsigned)o2 | ((unsigned)o3 << 16);
    *(v2u*)(midb + ((size_t)(n * T + t) * HWP + pix) * 256 + head * 32 + li * 4) = pk;
}

// ---------------------------------------------------------------------------
extern "C" void kernel_launch(void* const* d_in, const int* in_sizes, int n_in,
                              void* d_out, int out_size, void* d_ws, size_t ws_size,
                              hipStream_t stream) {
    const float* query  = (const float*)d_in[0];
    const float* refp   = (const float*)d_in[1];
    const float* inputf = (const float*)d_in[2];
    const unsigned char* mask = (const unsigned char*)d_in[5];
    const float* ff     = (const float*)d_in[6];
    const float* fb     = (const float*)d_in[7];
    const float* w_off  = (const float*)d_in[8];
    const float* b_off  = (const float*)d_in[9];
    const float* w_attn = (const float*)d_in[10];
    const float* b_attn = (const float*)d_in[11];
    const float* w_val  = (const float*)d_in[12];
    const float* b_val  = (const float*)d_in[13];
    const float* w_out  = (const float*)d_in[14];
    const float* b_out  = (const float*)d_in[15];

    char* w = (char*)d_ws;
    float* offb  = (float*)w;           w += (size_t)BS*LQ*192*4;
    float* attnb = (float*)w;           w += (size_t)BS*LQ*96*4;
    float* addb  = (float*)w;           w += (size_t)BS*3*HWP*6*4;
    unsigned short* V      = (unsigned short*)w; w += (size_t)48*HWP*DH*2;
    unsigned short* inb_q  = (unsigned short*)w; w += (size_t)NIMG*HWP*256*2;
    unsigned short* inb_v  = (unsigned short*)w; w += (size_t)NIMG*HWP*256*2;
    unsigned short* midb   = inb_v;  // alias: value conv done reading before sampler writes
    unsigned short* Wb_val = (unsigned short*)w; w += (size_t)9*256*256*2;
    unsigned short* Wb_oa  = (unsigned short*)w; w += (size_t)9*288*256*2;
    unsigned short* Wb_out = (unsigned short*)w; w += (size_t)9*256*256*2;
    float* outp = (float*)d_out;

    flow_kernel<<<(BS*HWP + 255)/256, 256, 0, stream>>>(ff, fb, addb);
    wcvt2_kernel<<<9*256, 256, 0, stream>>>(w_val, w_val, Wb_val, 256, 256);
    wcvt2_kernel<<<9*288, 256, 0, stream>>>(w_off, w_attn, Wb_oa, 192, 288);
    wcvt2_kernel<<<9*256, 256, 0, stream>>>(w_out, w_out, Wb_out, 256, 256);
    tcvt_kernel<<<dim3(HWP/32, 8, NIMG), 256, 0, stream>>>(inputf, inb_v);
    tcvt_kernel<<<dim3(HWP/32, 8, NIMG), 256, 0, stream>>>(query,  inb_q);

    convmfma<256,0><<<dim3(8, 18, NIMG), 256, 0, stream>>>(inb_v, Wb_val, b_val, nullptr, (void*)V, nullptr, mask);
    convmfma<288,1><<<dim3(9, 18, NIMG), 256, 0, stream>>>(inb_q, Wb_oa, b_off, b_attn, (void*)offb, (void*)attnb, nullptr);

    sample_kernel<<<(BS*LQ*NH)/32, 256, 0, stream>>>(V, offb, attnb, addb, refp, midb);

    convmfma<256,3><<<dim3(8, 18, NIMG), 256, 0, stream>>>(midb, Wb_out, b_out, nullptr, (void*)outp, nullptr, nullptr);
}

// Round 4
// 180.866 us; speedup vs baseline: 15.5238x; 2.4430x over previous
//
#include <hip/hip_runtime.h>
#include <hip/hip_bf16.h>

#define BS   2
#define T    3
#define CCH  256
#define HH   48
#define WW   48
#define NH   8
#define NP   4
#define NL   3
#define DH   32
#define HWP  (HH*WW)     // 2304
#define LQ   (T*HWP)     // 6912
#define NIMG (BS*T)      // 6

typedef short v8s __attribute__((ext_vector_type(8)));
typedef float v4f __attribute__((ext_vector_type(4)));
typedef float v2f __attribute__((ext_vector_type(2)));
typedef unsigned int v2u __attribute__((ext_vector_type(2)));

__device__ __forceinline__ unsigned short f2b(float f) {
    unsigned u = __float_as_uint(f);
    return (unsigned short)((u + 0x7FFFu + ((u >> 16) & 1u)) >> 16);
}

#define GLOAD_LDS16(gp, lp) \
    __builtin_amdgcn_global_load_lds((const __attribute__((address_space(1))) unsigned int*)(const void*)(gp), \
                                     (__attribute__((address_space(3))) unsigned int*)(void*)(lp), 16, 0, 0)

// ---------------------------------------------------------------------------
// Flow kernel: builds add[n][t][pix][l][2]  (fp32, tiny)
// ---------------------------------------------------------------------------
__global__ __launch_bounds__(256) void flow_kernel(
    const float* __restrict__ ff, const float* __restrict__ fb,
    float* __restrict__ addb)
{
    int idx = blockIdx.x * 256 + threadIdx.x;
    if (idx >= BS * HWP) return;
    int n = idx / HWP, pix = idx % HWP;
    int y = pix / WW, x = pix % WW;

    auto F = [&](const float* base, int i, int c, int p) {
        return base[n * (2*2*HWP) + i * (2*HWP) + c * HWP + p];
    };

    float f01x = F(ff,0,0,pix), f01y = F(ff,0,1,pix);
    float f12x = F(ff,1,0,pix), f12y = F(ff,1,1,pix);
    float b10x = F(fb,0,0,pix), b10y = F(fb,0,1,pix);
    float b21x = F(fb,1,0,pix), b21y = F(fb,1,1,pix);

    auto bil = [&](const float* base, int i, float fx, float fy, float* ox, float* oy) {
        float vx = (float)x + fx;
        float vy = (float)y + fy;
        float gx = 2.0f * vx / (float)(WW - 1) - 1.0f;
        float gy = 2.0f * vy / (float)(HH - 1) - 1.0f;
        float px = (gx + 1.0f) * 0.5f * (float)(WW - 1);
        float py = (gy + 1.0f) * 0.5f * (float)(HH - 1);
        px = fminf(fmaxf(px, 0.0f), (float)(WW - 1));
        py = fminf(fmaxf(py, 0.0f), (float)(HH - 1));
        float x0f = floorf(px), y0f = floorf(py);
        float wx1 = px - x0f, wx0 = 1.0f - wx1;
        float wy1 = py - y0f, wy0 = 1.0f - wy1;
        int xi0 = (int)x0f, yi0 = (int)y0f;
        int xc0 = min(max(xi0, 0), WW-1), xc1 = min(max(xi0+1, 0), WW-1);
        int yc0 = min(max(yi0, 0), HH-1), yc1 = min(max(yi0+1, 0), HH-1);
        float r[2];
        #pragma unroll
        for (int c = 0; c < 2; ++c) {
            float v00 = F(base, i, c, yc0*WW + xc0);
            float v10 = F(base, i, c, yc0*WW + xc1);
            float v01 = F(base, i, c, yc1*WW + xc0);
            float v11 = F(base, i, c, yc1*WW + xc1);
            r[c] = v00*(wx0*wy0) + v10*(wx1*wy0) + v01*(wx0*wy1) + v11*(wx1*wy1);
        }
        *ox = r[0]; *oy = r[1];
    };

    float wfx, wfy; bil(ff, 1, f01x, f01y, &wfx, &wfy);
    float f02x = f01x + wfx, f02y = f01y + wfy;
    float wbx, wby; bil(fb, 0, b21x, b21y, &wbx, &wby);
    float b20x = b21x + wbx, b20y = b21y + wby;

    float* A = addb + n * (3*HWP*6) + pix * 6;
    const int TS = HWP * 6;
    A[0] = 0.f;   A[1] = 0.f;   A[2] = f01x; A[3] = f01y; A[4] = f02x; A[5] = f02y;
    A[TS+0] = b10x; A[TS+1] = b10y; A[TS+2] = 0.f; A[TS+3] = 0.f; A[TS+4] = f12x; A[TS+5] = f12y;
    A[2*TS+0] = b20x; A[2*TS+1] = b20y; A[2*TS+2] = b21x; A[2*TS+3] = b21y; A[2*TS+4] = 0.f; A[2*TS+5] = 0.f;
}

// ---------------------------------------------------------------------------
// Weight transform: rows [0,M0) from s0, [M0,M1) from s1, [M1,Mpad) zero.
// dst[k][oc][ic] bf16.
// ---------------------------------------------------------------------------
__global__ __launch_bounds__(256) void wcvt2_kernel(
    const float* __restrict__ s0, const float* __restrict__ s1,
    unsigned short* __restrict__ dst, int M0, int M1, int Mpad)
{
    int idx = blockIdx.x * 256 + threadIdx.x;
    if (idx >= 9 * Mpad * 256) return;
    int k  = idx / (Mpad * 256);
    int oc = (idx / 256) % Mpad;
    int ic = idx % 256;
    float v = (oc < M0) ? s0[((size_t)oc * 256 + ic) * 9 + k]
            : (oc < M1) ? s1[((size_t)(oc - M0) * 256 + ic) * 9 + k] : 0.f;
    dst[idx] = f2b(v);
}

// ---------------------------------------------------------------------------
// Input transform: in[img][ic][px] fp32 -> out[img][px][ic] bf16
// ---------------------------------------------------------------------------
__global__ __launch_bounds__(256) void tcvt_kernel(
    const float* __restrict__ src, unsigned short* __restrict__ dst)
{
    __shared__ float lds[32][33];
    int px0 = blockIdx.x * 32, ic0 = blockIdx.y * 32, img = blockIdx.z;
    int t = threadIdx.x;
    #pragma unroll
    for (int s = 0; s < 4; ++s) {
        int icl = (t >> 5) + s * 8, pxl = t & 31;
        lds[icl][pxl] = src[((size_t)img * 256 + ic0 + icl) * HWP + px0 + pxl];
    }
    __syncthreads();
    #pragma unroll
    for (int s = 0; s < 4; ++s) {
        int pxl = (t >> 5) + s * 8, icl = t & 31;
        dst[((size_t)img * HWP + px0 + pxl) * 256 + ic0 + icl] = f2b(lds[icl][pxl]);
    }
}

// ---------------------------------------------------------------------------
// m97-structure implicit-GEMM conv: 128oc x 128px tile, BK=64, 4 waves.
// LDS: A 16KB + B 16KB, single buffer, 2 barriers/step.
// Staging: global_load_lds width-16; im2col + border-zero via per-lane SOURCE
// address (OOB -> zbuf). T2 swizzle via inverse-swizzled source col.
// phase 0: blocks [0,216) value conv (cls0), [216,540) off+attn conv (cls1)
// phase 1: out conv (cls2), 216 blocks.
// ---------------------------------------------------------------------------
__global__ __launch_bounds__(256) void convbig(
    int phase,
    const unsigned short* __restrict__ in_a,   // value input / mid input
    const unsigned short* __restrict__ in_b,   // query input
    const unsigned short* __restrict__ Wb_a,   // Wb_val / Wb_out
    const unsigned short* __restrict__ Wb_b,   // Wb_oa (Mpad=384)
    const float* __restrict__ bias_a,          // b_val / b_out
    const float* __restrict__ bias_off,
    const float* __restrict__ bias_attn,
    const unsigned short* __restrict__ zbuf,   // >=256B zeros
    unsigned short* __restrict__ Vout,
    float* __restrict__ offb,
    float* __restrict__ attnb,
    float* __restrict__ outp,
    const unsigned char* __restrict__ mask)
{
    __shared__ char lds[32768];

    const int tid  = threadIdx.x;
    const int lane = tid & 63;
    const int wv   = tid >> 6;

    int b = blockIdx.x;
    int cls, mt, nt, img, Mpad;
    const unsigned short *inb, *Wb;
    if (phase == 0) {
        if (b < 216) { cls = 0; mt = b % 2; int r = b / 2; nt = r % 18; img = r / 18;
                       inb = in_a; Wb = Wb_a; Mpad = 256; }
        else { b -= 216; cls = 1; mt = b % 3; int r = b / 3; nt = r % 18; img = r / 18;
               inb = in_b; Wb = Wb_b; Mpad = 384; }
    } else { cls = 2; mt = b % 2; int r = b / 2; nt = r % 18; img = r / 18;
             inb = in_a; Wb = Wb_a; Mpad = 256; }

    const int oc0 = mt * 128;
    const int pxb = nt * 128;
    const char* inIc = (const char*)(inb + (size_t)img * HWP * 256);
    const char* Wbc  = (const char*)Wb;
    const char* zbc  = (const char*)zbuf;

    // ---- stage geometry (per lane) ----
    const int rgrp  = lane >> 3;                       // row within 8-row group
    const int colsw = (((lane & 7) ^ rgrp) << 4);      // inverse-swizzled source col (bytes)
    int ypx[4], xpx[4], arow[4];
    #pragma unroll
    for (int j = 0; j < 4; ++j) {
        int r = wv * 32 + j * 8 + rgrp;
        int px = pxb + r;
        ypx[j] = px / 48;
        xpx[j] = px % 48;
        arow[j] = oc0 + r;
    }

    // ---- frag-read geometry ----
    const int rowl = lane & 15;
    const int g    = lane >> 4;
    const int keyx = (rowl & 7) << 4;
    const int aoff0 = ((wv >> 1) * 64 + rowl) * 128;
    const int boff0 = 16384 + ((wv & 1) * 64 + rowl) * 128;

    v4f acc[4][4];
    #pragma unroll
    for (int m = 0; m < 4; ++m)
        #pragma unroll
        for (int p = 0; p < 4; ++p)
            #pragma unroll
            for (int e = 0; e < 4; ++e) acc[m][p][e] = 0.f;

    for (int k = 0; k < 9; ++k) {
        const int dy = k / 3 - 1, dx = k % 3 - 1;
        const char* wk = Wbc + (size_t)k * Mpad * 512;
        const char* bsrc[4];
        #pragma unroll
        for (int j = 0; j < 4; ++j) {
            int ys = ypx[j] + dy, xs = xpx[j] + dx;
            bool val = ((unsigned)xs < 48u) && ((unsigned)ys < 48u);
            bsrc[j] = val ? (inIc + (size_t)(ys * 48 + xs) * 512 + colsw)
                          : (zbc + colsw);
        }

        for (int ic0 = 0; ic0 < 256; ic0 += 64) {
            __syncthreads();
            #pragma unroll
            for (int j = 0; j < 4; ++j) {
                GLOAD_LDS16(wk + (size_t)arow[j] * 512 + ic0 * 2 + colsw,
                            lds + (wv * 32 + j * 8) * 128);
            }
            #pragma unroll
            for (int j = 0; j < 4; ++j) {
                const char* s = bsrc[j];
                // ic0*2 byte offset only applies to valid (non-zbuf) sources
                GLOAD_LDS16((s == zbc + colsw) ? s : (s + ic0 * 2),
                            lds + 16384 + (wv * 32 + j * 8) * 128);
            }
            __syncthreads();

            #pragma unroll
            for (int kk = 0; kk < 2; ++kk) {
                const int colx = ((kk * 64 + g * 16) ^ keyx);
                v8s a[4], bfr[4];
                #pragma unroll
                for (int m = 0; m < 4; ++m)
                    a[m] = *(const v8s*)(lds + aoff0 + m * 2048 + colx);
                #pragma unroll
                for (int p = 0; p < 4; ++p)
                    bfr[p] = *(const v8s*)(lds + boff0 + p * 2048 + colx);
                #pragma unroll
                for (int m = 0; m < 4; ++m)
                    #pragma unroll
                    for (int p = 0; p < 4; ++p)
                        acc[m][p] = __builtin_amdgcn_mfma_f32_16x16x32_bf16(a[m], bfr[p], acc[m][p], 0, 0, 0);
            }
        }
    }

    // ---- epilogue ----
    const int n = img / T, t = img % T;
    const int ocw = oc0 + (wv >> 1) * 64;
    const int pxw = pxb + (wv & 1) * 64;

    #pragma unroll
    for (int p = 0; p < 4; ++p) {
        const int px_f = pxw + p * 16 + rowl;
        const int q = t * HWP + px_f;
        bool mk = (cls == 0) ? (mask[n * LQ + q] != 0) : false;
        #pragma unroll
        for (int m = 0; m < 4; ++m) {
            const int oc_f = ocw + m * 16 + g * 4;
            if (cls == 0) {
                unsigned short o[4];
                #pragma unroll
                for (int r = 0; r < 4; ++r) {
                    float v = acc[m][p][r] + bias_a[oc_f + r];
                    if (mk) v = 0.f;
                    o[r] = f2b(v);
                }
                int head = oc_f >> 5, d0 = oc_f & 31;
                v2u pk;
                pk[0] = (unsigned)o[0] | ((unsigned)o[1] << 16);
                pk[1] = (unsigned)o[2] | ((unsigned)o[3] << 16);
                *(v2u*)(Vout + (((size_t)(t * BS + n) * NH + head) * HWP + px_f) * 32 + d0) = pk;
            } else if (cls == 1) {
                if (oc_f < 192) {
                    v4f v;
                    #pragma unroll
                    for (int r = 0; r < 4; ++r) v[r] = acc[m][p][r] + bias_off[oc_f + r];
                    *(v4f*)(offb + ((size_t)n * LQ + q) * 192 + oc_f) = v;
                } else if (oc_f < 288) {
                    v4f v;
                    #pragma unroll
                    for (int r = 0; r < 4; ++r) v[r] = acc[m][p][r] + bias_attn[oc_f - 192 + r];
                    *(v4f*)(attnb + ((size_t)n * LQ + q) * 96 + (oc_f - 192)) = v;
                }
            } else {
                #pragma unroll
                for (int r = 0; r < 4; ++r)
                    outp[((size_t)img * CCH + oc_f + r) * HWP + px_f] =
                        acc[m][p][r] + bias_a[oc_f + r];
            }
        }
    }
}

// ---------------------------------------------------------------------------
// Deformable sampling. 8-lane group per (n,q,head); lane owns 4 d-channels.
// ---------------------------------------------------------------------------
__global__ __launch_bounds__(256) void sample_kernel(
    const unsigned short* __restrict__ V,
    const float* __restrict__ offb,
    const float* __restrict__ attnb,
    const float* __restrict__ addb,
    const float* __restrict__ refp,
    unsigned short* __restrict__ midb)
{
    const int tid = threadIdx.x;
    const int gid = tid >> 3, li = tid & 7;
    const int pair = blockIdx.x * 32 + gid;
    const int head = pair & 7;
    const int nq = pair >> 3;
    const int n = nq / LQ, q = nq % LQ;
    const int t = q / HWP, pix = q % HWP;

    const float* al = attnb + ((size_t)n * LQ + q) * 96 + head * 12;
    float lg[12];
    {
        v4f t0 = *(const v4f*)al, t1 = *(const v4f*)(al + 4), t2 = *(const v4f*)(al + 8);
        #pragma unroll
        for (int j = 0; j < 4; ++j) { lg[j] = t0[j]; lg[4+j] = t1[j]; lg[8+j] = t2[j]; }
    }
    const float* ofp = offb + ((size_t)n * LQ + q) * 192 + head * 24;
    float of[24];
    #pragma unroll
    for (int j = 0; j < 6; ++j) {
        v4f v = *(const v4f*)(ofp + j * 4);
        #pragma unroll
        for (int e = 0; e < 4; ++e) of[j*4+e] = v[e];
    }
    const float* rpp = refp + ((size_t)n * LQ + q) * 6;
    const float* adp = addb + ((size_t)n * 3 * HWP + t * HWP + pix) * 6;
    float rp[6], ad[6];
    #pragma unroll
    for (int j = 0; j < 3; ++j) {
        v2f r = *(const v2f*)(rpp + j * 2);
        v2f a = *(const v2f*)(adp + j * 2);
        rp[j*2] = r[0]; rp[j*2+1] = r[1];
        ad[j*2] = a[0]; ad[j*2+1] = a[1];
    }

    float m = lg[0];
    #pragma unroll
    for (int j = 1; j < 12; ++j) m = fmaxf(m, lg[j]);
    float s = 0.f;
    #pragma unroll
    for (int j = 0; j < 12; ++j) { lg[j] = expf(lg[j] - m); s += lg[j]; }
    float inv = 1.0f / s;
    #pragma unroll
    for (int j = 0; j < 12; ++j) lg[j] *= inv;

    float acc0 = 0.f, acc1 = 0.f, acc2 = 0.f, acc3 = 0.f;

    #pragma unroll
    for (int l = 0; l < 3; ++l) {
        float refx = rp[l*2+0], refy = rp[l*2+1];
        float addx = ad[l*2+0], addy = ad[l*2+1];
        const unsigned short* Vi =
            V + (size_t)((l * BS + n) * NH + head) * HWP * DH + li * 4;
        #pragma unroll
        for (int p = 0; p < 4; ++p) {
            float ox = of[(l*4+p)*2+0] + addx;
            float oy = of[(l*4+p)*2+1] + addy;
            float locx = refx + ox * (1.0f/48.0f);
            float locy = refy + oy * (1.0f/48.0f);
            float gx = 2.0f*locx - 1.0f;
            float gy = 2.0f*locy - 1.0f;
            float pxf = ((gx + 1.0f) * 48.0f - 1.0f) * 0.5f;
            float pyf = ((gy + 1.0f) * 48.0f - 1.0f) * 0.5f;
            float x0f = floorf(pxf), y0f = floorf(pyf);
            float wx1 = pxf - x0f, wx0 = 1.0f - wx1;
            float wy1 = pyf - y0f, wy0 = 1.0f - wy1;
            int xi0 = (int)x0f, yi0 = (int)y0f;
            bool vx0 = (x0f >= 0.0f)     && (x0f <= 47.0f);
            bool vx1 = (x0f+1.f >= 0.0f) && (x0f+1.f <= 47.0f);
            bool vy0 = (y0f >= 0.0f)     && (y0f <= 47.0f);
            bool vy1 = (y0f+1.f >= 0.0f) && (y0f+1.f <= 47.0f);
            int xc0 = min(max(xi0, 0), 47),   xc1 = min(max(xi0+1, 0), 47);
            int yc0 = min(max(yi0, 0), 47),   yc1 = min(max(yi0+1, 0), 47);
            float aw = lg[l*4+p];
            float w00 = (vx0 && vy0) ? wx0*wy0*aw : 0.f;
            float w10 = (vx1 && vy0) ? wx1*wy0*aw : 0.f;
            float w01 = (vx0 && vy1) ? wx0*wy1*aw : 0.f;
            float w11 = (vx1 && vy1) ? wx1*wy1*aw : 0.f;
            v2u u00 = *(const v2u*)(Vi + (yc0*WW + xc0)*DH);
            v2u u10 = *(const v2u*)(Vi + (yc0*WW + xc1)*DH);
            v2u u01 = *(const v2u*)(Vi + (yc1*WW + xc0)*DH);
            v2u u11 = *(const v2u*)(Vi + (yc1*WW + xc1)*DH);
            #pragma unroll
            for (int c = 0; c < 4; ++c) {
                v2u u = (c == 0) ? u00 : (c == 1) ? u10 : (c == 2) ? u01 : u11;
                float w = (c == 0) ? w00 : (c == 1) ? w10 : (c == 2) ? w01 : w11;
                float f0 = __uint_as_float(u[0] << 16);
                float f1 = __uint_as_float(u[0] & 0xFFFF0000u);
                float f2 = __uint_as_float(u[1] << 16);
                float f3 = __uint_as_float(u[1] & 0xFFFF0000u);
                acc0 += w * f0; acc1 += w * f1; acc2 += w * f2; acc3 += w * f3;
            }
        }
    }

    unsigned short o0 = f2b(acc0), o1 = f2b(acc1), o2 = f2b(acc2), o3 = f2b(acc3);
    v2u pk;
    pk[0] = (unsigned)o0 | ((unsigned)o1 << 16);
    pk[1] = (unsigned)o2 | ((unsigned)o3 << 16);
    *(v2u*)(midb + ((size_t)(n * T + t) * HWP + pix) * 256 + head * 32 + li * 4) = pk;
}

// ---------------------------------------------------------------------------
extern "C" void kernel_launch(void* const* d_in, const int* in_sizes, int n_in,
                              void* d_out, int out_size, void* d_ws, size_t ws_size,
                              hipStream_t stream) {
    const float* query  = (const float*)d_in[0];
    const float* refp   = (const float*)d_in[1];
    const float* inputf = (const float*)d_in[2];
    const unsigned char* mask = (const unsigned char*)d_in[5];
    const float* ff     = (const float*)d_in[6];
    const float* fb     = (const float*)d_in[7];
    const float* w_off  = (const float*)d_in[8];
    const float* b_off  = (const float*)d_in[9];
    const float* w_attn = (const float*)d_in[10];
    const float* b_attn = (const float*)d_in[11];
    const float* w_val  = (const float*)d_in[12];
    const float* b_val  = (const float*)d_in[13];
    const float* w_out  = (const float*)d_in[14];
    const float* b_out  = (const float*)d_in[15];

    char* w = (char*)d_ws;
    float* offb  = (float*)w;           w += (size_t)BS*LQ*192*4;
    float* attnb = (float*)w;           w += (size_t)BS*LQ*96*4;
    float* addb  = (float*)w;           w += (size_t)BS*3*HWP*6*4;
    unsigned short* V      = (unsigned short*)w; w += (size_t)48*HWP*DH*2;
    unsigned short* inb_q  = (unsigned short*)w; w += (size_t)NIMG*HWP*256*2;
    unsigned short* inb_v  = (unsigned short*)w; w += (size_t)NIMG*HWP*256*2;
    unsigned short* midb   = inb_v;  // alias: value conv done reading before sampler writes
    unsigned short* Wb_val = (unsigned short*)w; w += (size_t)9*256*256*2;
    unsigned short* Wb_oa  = (unsigned short*)w; w += (size_t)9*384*256*2;
    unsigned short* Wb_out = (unsigned short*)w; w += (size_t)9*256*256*2;
    unsigned short* zbuf   = (unsigned short*)w; w += 256;
    float* outp = (float*)d_out;

    hipMemsetAsync(zbuf, 0, 256, stream);
    flow_kernel<<<(BS*HWP + 255)/256, 256, 0, stream>>>(ff, fb, addb);
    wcvt2_kernel<<<9*256, 256, 0, stream>>>(w_val, w_val, Wb_val, 256, 256, 256);
    wcvt2_kernel<<<9*384, 256, 0, stream>>>(w_off, w_attn, Wb_oa, 192, 288, 384);
    wcvt2_kernel<<<9*256, 256, 0, stream>>>(w_out, w_out, Wb_out, 256, 256, 256);
    tcvt_kernel<<<dim3(HWP/32, 8, NIMG), 256, 0, stream>>>(inputf, inb_v);
    tcvt_kernel<<<dim3(HWP/32, 8, NIMG), 256, 0, stream>>>(query,  inb_q);

    convbig<<<540, 256, 0, stream>>>(0, inb_v, inb_q, Wb_val, Wb_oa,
                                     b_val, b_off, b_attn, zbuf,
                                     V, offb, attnb, nullptr, mask);

    sample_kernel<<<(BS*LQ*NH)/32, 256, 0, stream>>>(V, offb, attnb, addb, refp, midb);

    convbig<<<216, 256, 0, stream>>>(1, midb, nullptr, Wb_out, nullptr,
                                     b_out, nullptr, nullptr, zbuf,
                                     nullptr, nullptr, nullptr, outp, nullptr);
}

// Round 5
// 156.839 us; speedup vs baseline: 17.9020x; 1.1532x over previous
//
#include <hip/hip_runtime.h>
#include <hip/hip_bf16.h>

#define BS   2
#define T    3
#define CCH  256
#define HH   48
#define WW   48
#define NH   8
#define NP   4
#define NL   3
#define DH   32
#define HWP  (HH*WW)     // 2304
#define LQ   (T*HWP)     // 6912
#define NIMG (BS*T)      // 6

typedef short v8s __attribute__((ext_vector_type(8)));
typedef float v4f __attribute__((ext_vector_type(4)));
typedef float v2f __attribute__((ext_vector_type(2)));
typedef unsigned int v2u __attribute__((ext_vector_type(2)));

__device__ __forceinline__ unsigned short f2b(float f) {
    unsigned u = __float_as_uint(f);
    return (unsigned short)((u + 0x7FFFu + ((u >> 16) & 1u)) >> 16);
}

#define GLOAD_LDS16(gp, lp) \
    __builtin_amdgcn_global_load_lds((const __attribute__((address_space(1))) unsigned int*)(const void*)(gp), \
                                     (__attribute__((address_space(3))) unsigned int*)(void*)(lp), 16, 0, 0)

// LDS layout (bytes): Abuf0 @0 (16K), Abuf1 @16384, slab @32768 (288*128=36864),
// zero-row @69632 (128). Total 69760 -> 2 blocks/CU.
#define LDS_SLAB  32768
#define LDS_ZROW  69632
#define LDS_TOTAL 69760

// ---------------------------------------------------------------------------
// Flow kernel: builds add[n][t][pix][l][2]  (fp32, tiny)
// ---------------------------------------------------------------------------
__global__ __launch_bounds__(256) void flow_kernel(
    const float* __restrict__ ff, const float* __restrict__ fb,
    float* __restrict__ addb)
{
    int idx = blockIdx.x * 256 + threadIdx.x;
    if (idx >= BS * HWP) return;
    int n = idx / HWP, pix = idx % HWP;
    int y = pix / WW, x = pix % WW;

    auto F = [&](const float* base, int i, int c, int p) {
        return base[n * (2*2*HWP) + i * (2*HWP) + c * HWP + p];
    };

    float f01x = F(ff,0,0,pix), f01y = F(ff,0,1,pix);
    float f12x = F(ff,1,0,pix), f12y = F(ff,1,1,pix);
    float b10x = F(fb,0,0,pix), b10y = F(fb,0,1,pix);
    float b21x = F(fb,1,0,pix), b21y = F(fb,1,1,pix);

    auto bil = [&](const float* base, int i, float fx, float fy, float* ox, float* oy) {
        float vx = (float)x + fx;
        float vy = (float)y + fy;
        float gx = 2.0f * vx / (float)(WW - 1) - 1.0f;
        float gy = 2.0f * vy / (float)(HH - 1) - 1.0f;
        float px = (gx + 1.0f) * 0.5f * (float)(WW - 1);
        float py = (gy + 1.0f) * 0.5f * (float)(HH - 1);
        px = fminf(fmaxf(px, 0.0f), (float)(WW - 1));
        py = fminf(fmaxf(py, 0.0f), (float)(HH - 1));
        float x0f = floorf(px), y0f = floorf(py);
        float wx1 = px - x0f, wx0 = 1.0f - wx1;
        float wy1 = py - y0f, wy0 = 1.0f - wy1;
        int xi0 = (int)x0f, yi0 = (int)y0f;
        int xc0 = min(max(xi0, 0), WW-1), xc1 = min(max(xi0+1, 0), WW-1);
        int yc0 = min(max(yi0, 0), HH-1), yc1 = min(max(yi0+1, 0), HH-1);
        float r[2];
        #pragma unroll
        for (int c = 0; c < 2; ++c) {
            float v00 = F(base, i, c, yc0*WW + xc0);
            float v10 = F(base, i, c, yc0*WW + xc1);
            float v01 = F(base, i, c, yc1*WW + xc0);
            float v11 = F(base, i, c, yc1*WW + xc1);
            r[c] = v00*(wx0*wy0) + v10*(wx1*wy0) + v01*(wx0*wy1) + v11*(wx1*wy1);
        }
        *ox = r[0]; *oy = r[1];
    };

    float wfx, wfy; bil(ff, 1, f01x, f01y, &wfx, &wfy);
    float f02x = f01x + wfx, f02y = f01y + wfy;
    float wbx, wby; bil(fb, 0, b21x, b21y, &wbx, &wby);
    float b20x = b21x + wbx, b20y = b21y + wby;

    float* A = addb + n * (3*HWP*6) + pix * 6;
    const int TS = HWP * 6;
    A[0] = 0.f;   A[1] = 0.f;   A[2] = f01x; A[3] = f01y; A[4] = f02x; A[5] = f02y;
    A[TS+0] = b10x; A[TS+1] = b10y; A[TS+2] = 0.f; A[TS+3] = 0.f; A[TS+4] = f12x; A[TS+5] = f12y;
    A[2*TS+0] = b20x; A[2*TS+1] = b20y; A[2*TS+2] = b21x; A[2*TS+3] = b21y; A[2*TS+4] = 0.f; A[2*TS+5] = 0.f;
}

// ---------------------------------------------------------------------------
// Weight transform: rows [0,M0) from s0, [M0,M1) from s1, [M1,Mpad) zero.
// dst[k][oc][ic] bf16.
// ---------------------------------------------------------------------------
__global__ __launch_bounds__(256) void wcvt2_kernel(
    const float* __restrict__ s0, const float* __restrict__ s1,
    unsigned short* __restrict__ dst, int M0, int M1, int Mpad)
{
    int idx = blockIdx.x * 256 + threadIdx.x;
    if (idx >= 9 * Mpad * 256) return;
    int k  = idx / (Mpad * 256);
    int oc = (idx / 256) % Mpad;
    int ic = idx % 256;
    float v = (oc < M0) ? s0[((size_t)oc * 256 + ic) * 9 + k]
            : (oc < M1) ? s1[((size_t)(oc - M0) * 256 + ic) * 9 + k] : 0.f;
    dst[idx] = f2b(v);
}

// ---------------------------------------------------------------------------
// Input transform: in[img][ic][px] fp32 -> out[img][px][ic] bf16
// ---------------------------------------------------------------------------
__global__ __launch_bounds__(256) void tcvt_kernel(
    const float* __restrict__ src, unsigned short* __restrict__ dst)
{
    __shared__ float lds[32][33];
    int px0 = blockIdx.x * 32, ic0 = blockIdx.y * 32, img = blockIdx.z;
    int t = threadIdx.x;
    #pragma unroll
    for (int s = 0; s < 4; ++s) {
        int icl = (t >> 5) + s * 8, pxl = t & 31;
        lds[icl][pxl] = src[((size_t)img * 256 + ic0 + icl) * HWP + px0 + pxl];
    }
    __syncthreads();
    #pragma unroll
    for (int s = 0; s < 4; ++s) {
        int pxl = (t >> 5) + s * 8, icl = t & 31;
        dst[((size_t)img * HWP + px0 + pxl) * 256 + ic0 + icl] = f2b(lds[icl][pxl]);
    }
}

// ---------------------------------------------------------------------------
// Slab implicit-GEMM conv: 128oc x 128px tile, 4 waves (64oc x 64px each).
// Per ic-chunk (64 ch): stage input slab ONCE (288 px incl. halo rows,
// contiguous in flattened px space), then loop 9 taps with double-buffered
// weight staging + counted vmcnt (A[k+1] in flight across barriers).
// B-fragments read shifted from slab; OOB -> LDS zero-row (SAME border).
// ---------------------------------------------------------------------------
__global__ __launch_bounds__(256) void convbig(
    int phase,
    const unsigned short* __restrict__ in_a,   // value input / mid input
    const unsigned short* __restrict__ in_b,   // query input
    const unsigned short* __restrict__ Wb_a,   // Wb_val / Wb_out
    const unsigned short* __restrict__ Wb_b,   // Wb_oa (Mpad=384)
    const float* __restrict__ bias_a,
    const float* __restrict__ bias_off,
    const float* __restrict__ bias_attn,
    unsigned short* __restrict__ Vout,
    float* __restrict__ offb,
    float* __restrict__ attnb,
    float* __restrict__ outp,
    const unsigned char* __restrict__ mask)
{
    __shared__ __align__(16) char lds[LDS_TOTAL];

    const int tid  = threadIdx.x;
    const int lane = tid & 63;
    const int wv   = tid >> 6;

    int b = blockIdx.x;
    int cls, mt, nt, img, Mpad;
    const unsigned short *inb, *Wb;
    if (phase == 0) {
        if (b < 216) { cls = 0; mt = b % 2; int r = b / 2; nt = r % 18; img = r / 18;
                       inb = in_a; Wb = Wb_a; Mpad = 256; }
        else { b -= 216; cls = 1; mt = b % 3; int r = b / 3; nt = r % 18; img = r / 18;
               inb = in_b; Wb = Wb_b; Mpad = 384; }
    } else { cls = 2; mt = b % 2; int r = b / 2; nt = r % 18; img = r / 18;
             inb = in_a; Wb = Wb_a; Mpad = 256; }

    const int oc0 = mt * 128;
    const int pxb = nt * 128;
    const char* inIc = (const char*)(inb + (size_t)img * HWP * 256);
    const char* Wbc  = (const char*)Wb;

    // zero-row init (once; visible after first chunk's full drain + barrier)
    if (tid < 8) {
        v8s z;
        #pragma unroll
        for (int j = 0; j < 8; ++j) z[j] = 0;
        *(v8s*)(lds + LDS_ZROW + tid * 16) = z;
    }

    // slab geometry
    const int r0   = pxb / 48;
    const int rlo  = (r0 > 0) ? (r0 - 1) : 0;
    const int pxlo = rlo * 48;

    // staging lane geometry
    const int lrow8 = lane >> 3;     // 0..7
    const int lcol  = lane & 7;

    // fragment geometry
    const int rowl = lane & 15;
    const int g    = lane >> 4;
    const int keyx = (rowl & 7) << 4;
    const int aoff0 = ((wv >> 1) * 64 + rowl) * 128;
    const int pxw   = pxb + (wv & 1) * 64;
    int ypx[4], xpx[4];
    #pragma unroll
    for (int p = 0; p < 4; ++p) {
        int px = pxw + p * 16 + rowl;
        ypx[p] = px / 48;
        xpx[p] = px % 48;
    }
    // A staging rows (per thread)
    int ocr_[4];
    #pragma unroll
    for (int j = 0; j < 4; ++j) ocr_[j] = j * 32 + wv * 8 + lrow8;

    v4f acc[4][4];
    #pragma unroll
    for (int m = 0; m < 4; ++m)
        #pragma unroll
        for (int p = 0; p < 4; ++p)
            #pragma unroll
            for (int e = 0; e < 4; ++e) acc[m][p][e] = 0.f;

    for (int c = 0; c < 4; ++c) {
        const int ic0b = c * 128;   // byte offset of ic-chunk within 512B px row

        // ---- stage slab (288 px-entries x 128 B), linear dest, pre-swizzled src ----
        #pragma unroll
        for (int rr = 0; rr < 9; ++rr) {
            int pe  = rr * 32 + wv * 8 + lrow8;
            int gpx = pxlo + pe;
            if (gpx > 2303) gpx = 2303;
            GLOAD_LDS16(inIc + (size_t)gpx * 512 + ic0b + ((lcol ^ (pe & 7)) << 4),
                        lds + LDS_SLAB + (rr * 32 + wv * 8) * 128);
        }
        // ---- stage A tap0 -> buf0 ----
        #pragma unroll
        for (int j = 0; j < 4; ++j) {
            GLOAD_LDS16(Wbc + (size_t)(oc0 + ocr_[j]) * 512 + ic0b + ((lcol ^ (ocr_[j] & 7)) << 4),
                        lds + (j * 32 + wv * 8) * 128);
        }
        asm volatile("s_waitcnt vmcnt(0) lgkmcnt(0)" ::: "memory");
        __builtin_amdgcn_s_barrier();

        for (int k = 0; k < 9; ++k) {
            const int dy = k / 3 - 1, dx = k % 3 - 1;
            const int cur = k & 1;
            if (k < 8) {
                const char* wk1 = Wbc + (size_t)(k + 1) * Mpad * 512;
                #pragma unroll
                for (int j = 0; j < 4; ++j) {
                    GLOAD_LDS16(wk1 + (size_t)(oc0 + ocr_[j]) * 512 + ic0b + ((lcol ^ (ocr_[j] & 7)) << 4),
                                lds + (cur ^ 1) * 16384 + (j * 32 + wv * 8) * 128);
                }
                asm volatile("s_waitcnt vmcnt(4)" ::: "memory");
            } else {
                asm volatile("s_waitcnt vmcnt(0)" ::: "memory");
            }
            __builtin_amdgcn_s_barrier();

            // B addresses for this tap
            int bbase[4], bkey[4];
            #pragma unroll
            for (int p = 0; p < 4; ++p) {
                int ys = ypx[p] + dy, xs = xpx[p] + dx;
                bool val = ((unsigned)ys < 48u) && ((unsigned)xs < 48u);
                int pe = ys * 48 + xs - pxlo;
                bbase[p] = val ? (LDS_SLAB + pe * 128) : LDS_ZROW;
                bkey[p]  = val ? ((pe & 7) << 4) : 0;
            }

            #pragma unroll
            for (int kk = 0; kk < 2; ++kk) {
                const int col = kk * 64 + g * 16;
                v8s a[4], bfr[4];
                #pragma unroll
                for (int m = 0; m < 4; ++m)
                    a[m] = *(const v8s*)(lds + cur * 16384 + aoff0 + m * 2048 + (col ^ keyx));
                #pragma unroll
                for (int p = 0; p < 4; ++p)
                    bfr[p] = *(const v8s*)(lds + bbase[p] + (col ^ bkey[p]));
                #pragma unroll
                for (int m = 0; m < 4; ++m)
                    #pragma unroll
                    for (int p = 0; p < 4; ++p)
                        acc[m][p] = __builtin_amdgcn_mfma_f32_16x16x32_bf16(a[m], bfr[p], acc[m][p], 0, 0, 0);
            }
            __builtin_amdgcn_s_barrier();
        }
    }

    // ---- epilogue ----
    const int n = img / T, t = img % T;
    const int ocw = oc0 + (wv >> 1) * 64;

    #pragma unroll
    for (int p = 0; p < 4; ++p) {
        const int px_f = pxw + p * 16 + rowl;
        const int q = t * HWP + px_f;
        bool mk = (cls == 0) ? (mask[n * LQ + q] != 0) : false;
        #pragma unroll
        for (int m = 0; m < 4; ++m) {
            const int oc_f = ocw + m * 16 + g * 4;
            if (cls == 0) {
                unsigned short o[4];
                #pragma unroll
                for (int r = 0; r < 4; ++r) {
                    float v = acc[m][p][r] + bias_a[oc_f + r];
                    if (mk) v = 0.f;
                    o[r] = f2b(v);
                }
                int head = oc_f >> 5, d0 = oc_f & 31;
                v2u pk;
                pk[0] = (unsigned)o[0] | ((unsigned)o[1] << 16);
                pk[1] = (unsigned)o[2] | ((unsigned)o[3] << 16);
                *(v2u*)(Vout + (((size_t)(t * BS + n) * NH + head) * HWP + px_f) * 32 + d0) = pk;
            } else if (cls == 1) {
                if (oc_f < 192) {
                    v4f v;
                    #pragma unroll
                    for (int r = 0; r < 4; ++r) v[r] = acc[m][p][r] + bias_off[oc_f + r];
                    *(v4f*)(offb + ((size_t)n * LQ + q) * 192 + oc_f) = v;
                } else if (oc_f < 288) {
                    v4f v;
                    #pragma unroll
                    for (int r = 0; r < 4; ++r) v[r] = acc[m][p][r] + bias_attn[oc_f - 192 + r];
                    *(v4f*)(attnb + ((size_t)n * LQ + q) * 96 + (oc_f - 192)) = v;
                }
            } else {
                #pragma unroll
                for (int r = 0; r < 4; ++r)
                    outp[((size_t)img * CCH + oc_f + r) * HWP + px_f] =
                        acc[m][p][r] + bias_a[oc_f + r];
            }
        }
    }
}

// ---------------------------------------------------------------------------
// Deformable sampling. 8-lane group per (n,q,head); lane owns 4 d-channels.
// ---------------------------------------------------------------------------
__global__ __launch_bounds__(256) void sample_kernel(
    const unsigned short* __restrict__ V,
    const float* __restrict__ offb,
    const float* __restrict__ attnb,
    const float* __restrict__ addb,
    const float* __restrict__ refp,
    unsigned short* __restrict__ midb)
{
    const int tid = threadIdx.x;
    const int gid = tid >> 3, li = tid & 7;
    const int pair = blockIdx.x * 32 + gid;
    const int head = pair & 7;
    const int nq = pair >> 3;
    const int n = nq / LQ, q = nq % LQ;
    const int t = q / HWP, pix = q % HWP;

    const float* al = attnb + ((size_t)n * LQ + q) * 96 + head * 12;
    float lg[12];
    {
        v4f t0 = *(const v4f*)al, t1 = *(const v4f*)(al + 4), t2 = *(const v4f*)(al + 8);
        #pragma unroll
        for (int j = 0; j < 4; ++j) { lg[j] = t0[j]; lg[4+j] = t1[j]; lg[8+j] = t2[j]; }
    }
    const float* ofp = offb + ((size_t)n * LQ + q) * 192 + head * 24;
    float of[24];
    #pragma unroll
    for (int j = 0; j < 6; ++j) {
        v4f v = *(const v4f*)(ofp + j * 4);
        #pragma unroll
        for (int e = 0; e < 4; ++e) of[j*4+e] = v[e];
    }
    const float* rpp = refp + ((size_t)n * LQ + q) * 6;
    const float* adp = addb + ((size_t)n * 3 * HWP + t * HWP + pix) * 6;
    float rp[6], ad[6];
    #pragma unroll
    for (int j = 0; j < 3; ++j) {
        v2f r = *(const v2f*)(rpp + j * 2);
        v2f a = *(const v2f*)(adp + j * 2);
        rp[j*2] = r[0]; rp[j*2+1] = r[1];
        ad[j*2] = a[0]; ad[j*2+1] = a[1];
    }

    float m = lg[0];
    #pragma unroll
    for (int j = 1; j < 12; ++j) m = fmaxf(m, lg[j]);
    float s = 0.f;
    #pragma unroll
    for (int j = 0; j < 12; ++j) { lg[j] = expf(lg[j] - m); s += lg[j]; }
    float inv = 1.0f / s;
    #pragma unroll
    for (int j = 0; j < 12; ++j) lg[j] *= inv;

    float acc0 = 0.f, acc1 = 0.f, acc2 = 0.f, acc3 = 0.f;

    #pragma unroll
    for (int l = 0; l < 3; ++l) {
        float refx = rp[l*2+0], refy = rp[l*2+1];
        float addx = ad[l*2+0], addy = ad[l*2+1];
        const unsigned short* Vi =
            V + (size_t)((l * BS + n) * NH + head) * HWP * DH + li * 4;
        #pragma unroll
        for (int p = 0; p < 4; ++p) {
            float ox = of[(l*4+p)*2+0] + addx;
            float oy = of[(l*4+p)*2+1] + addy;
            float locx = refx + ox * (1.0f/48.0f);
            float locy = refy + oy * (1.0f/48.0f);
            float gx = 2.0f*locx - 1.0f;
            float gy = 2.0f*locy - 1.0f;
            float pxf = ((gx + 1.0f) * 48.0f - 1.0f) * 0.5f;
            float pyf = ((gy + 1.0f) * 48.0f - 1.0f) * 0.5f;
            float x0f = floorf(pxf), y0f = floorf(pyf);
            float wx1 = pxf - x0f, wx0 = 1.0f - wx1;
            float wy1 = pyf - y0f, wy0 = 1.0f - wy1;
            int xi0 = (int)x0f, yi0 = (int)y0f;
            bool vx0 = (x0f >= 0.0f)     && (x0f <= 47.0f);
            bool vx1 = (x0f+1.f >= 0.0f) && (x0f+1.f <= 47.0f);
            bool vy0 = (y0f >= 0.0f)     && (y0f <= 47.0f);
            bool vy1 = (y0f+1.f >= 0.0f) && (y0f+1.f <= 47.0f);
            int xc0 = min(max(xi0, 0), 47),   xc1 = min(max(xi0+1, 0), 47);
            int yc0 = min(max(yi0, 0), 47),   yc1 = min(max(yi0+1, 0), 47);
            float aw = lg[l*4+p];
            float w00 = (vx0 && vy0) ? wx0*wy0*aw : 0.f;
            float w10 = (vx1 && vy0) ? wx1*wy0*aw : 0.f;
            float w01 = (vx0 && vy1) ? wx0*wy1*aw : 0.f;
            float w11 = (vx1 && vy1) ? wx1*wy1*aw : 0.f;
            v2u u00 = *(const v2u*)(Vi + (yc0*WW + xc0)*DH);
            v2u u10 = *(const v2u*)(Vi + (yc0*WW + xc1)*DH);
            v2u u01 = *(const v2u*)(Vi + (yc1*WW + xc0)*DH);
            v2u u11 = *(const v2u*)(Vi + (yc1*WW + xc1)*DH);
            #pragma unroll
            for (int c = 0; c < 4; ++c) {
                v2u u = (c == 0) ? u00 : (c == 1) ? u10 : (c == 2) ? u01 : u11;
                float w = (c == 0) ? w00 : (c == 1) ? w10 : (c == 2) ? w01 : w11;
                float f0 = __uint_as_float(u[0] << 16);
                float f1 = __uint_as_float(u[0] & 0xFFFF0000u);
                float f2 = __uint_as_float(u[1] << 16);
                float f3 = __uint_as_float(u[1] & 0xFFFF0000u);
                acc0 += w * f0; acc1 += w * f1; acc2 += w * f2; acc3 += w * f3;
            }
        }
    }

    unsigned short o0 = f2b(acc0), o1 = f2b(acc1), o2 = f2b(acc2), o3 = f2b(acc3);
    v2u pk;
    pk[0] = (unsigned)o0 | ((unsigned)o1 << 16);
    pk[1] = (unsigned)o2 | ((unsigned)o3 << 16);
    *(v2u*)(midb + ((size_t)(n * T + t) * HWP + pix) * 256 + head * 32 + li * 4) = pk;
}

// ---------------------------------------------------------------------------
extern "C" void kernel_launch(void* const* d_in, const int* in_sizes, int n_in,
                              void* d_out, int out_size, void* d_ws, size_t ws_size,
                              hipStream_t stream) {
    const float* query  = (const float*)d_in[0];
    const float* refp   = (const float*)d_in[1];
    const float* inputf = (const float*)d_in[2];
    const unsigned char* mask = (const unsigned char*)d_in[5];
    const float* ff     = (const float*)d_in[6];
    const float* fb     = (const float*)d_in[7];
    const float* w_off  = (const float*)d_in[8];
    const float* b_off  = (const float*)d_in[9];
    const float* w_attn = (const float*)d_in[10];
    const float* b_attn = (const float*)d_in[11];
    const float* w_val  = (const float*)d_in[12];
    const float* b_val  = (const float*)d_in[13];
    const float* w_out  = (const float*)d_in[14];
    const float* b_out  = (const float*)d_in[15];

    char* w = (char*)d_ws;
    float* offb  = (float*)w;           w += (size_t)BS*LQ*192*4;
    float* attnb = (float*)w;           w += (size_t)BS*LQ*96*4;
    float* addb  = (float*)w;           w += (size_t)BS*3*HWP*6*4;
    unsigned short* V      = (unsigned short*)w; w += (size_t)48*HWP*DH*2;
    unsigned short* inb_q  = (unsigned short*)w; w += (size_t)NIMG*HWP*256*2;
    unsigned short* inb_v  = (unsigned short*)w; w += (size_t)NIMG*HWP*256*2;
    unsigned short* midb   = inb_v;  // alias: value conv done reading before sampler writes
    unsigned short* Wb_val = (unsigned short*)w; w += (size_t)9*256*256*2;
    unsigned short* Wb_oa  = (unsigned short*)w; w += (size_t)9*384*256*2;
    unsigned short* Wb_out = (unsigned short*)w; w += (size_t)9*256*256*2;
    float* outp = (float*)d_out;

    flow_kernel<<<(BS*HWP + 255)/256, 256, 0, stream>>>(ff, fb, addb);
    wcvt2_kernel<<<9*256, 256, 0, stream>>>(w_val, w_val, Wb_val, 256, 256, 256);
    wcvt2_kernel<<<9*384, 256, 0, stream>>>(w_off, w_attn, Wb_oa, 192, 288, 384);
    wcvt2_kernel<<<9*256, 256, 0, stream>>>(w_out, w_out, Wb_out, 256, 256, 256);
    tcvt_kernel<<<dim3(HWP/32, 8, NIMG), 256, 0, stream>>>(inputf, inb_v);
    tcvt_kernel<<<dim3(HWP/32, 8, NIMG), 256, 0, stream>>>(query,  inb_q);

    convbig<<<540, 256, 0, stream>>>(0, inb_v, inb_q, Wb_val, Wb_oa,
                                     b_val, b_off, b_attn,
                                     V, offb, attnb, nullptr, mask);

    sample_kernel<<<(BS*LQ*NH)/32, 256, 0, stream>>>(V, offb, attnb, addb, refp, midb);

    convbig<<<216, 256, 0, stream>>>(1, midb, nullptr, Wb_out, nullptr,
                                     b_out, nullptr, nullptr,
                                     nullptr, nullptr, nullptr, outp, nullptr);
}